// Round 4
// baseline (367.377 us; speedup 1.0000x reference)
//
#include <hip/hip_runtime.h>
#include <hip/hip_bf16.h>
#include <math.h>

#define NTOK   16384
#define NEXP   64
#define HID    4096
#define KSEL   8
#define EPS    7.5e-5f
#define NSPLIT 4
#define KSZ    (HID / NSPLIT)

typedef __attribute__((ext_vector_type(8))) short short8;
typedef __attribute__((ext_vector_type(4))) float f32x4;

// d_out element offsets (f32 elements; int outputs stored as float values)
#define O_LOGITS 0u
#define O_PROBS  1048576u
#define O_TIDX   1179648u
#define O_GROUP  1310720u
#define O_IDX    1310784u
#define O_TPE    1441856u
#define O_LB     1441920u
#define O_ZL     1441921u

// ws byte offsets
#define W_CQ      0u          // 256 int: counts[q][e], q = row>>12
#define W_GCOUNT  1024u       // 1 int
#define W_BARS    1040u       // 3 int grid-barrier counters
#define W_OFFS2   2048u       // 256 int: offsets[e][q]
#define W_LSQP    4096u       // 256 f32 per-block z-loss partials
#define W_LIST    8192u       // 16384 int flagged rows
#define W_PSUM    73728u      // 256*64 f32 per-block probsum partials
#define W_FLAT    147456u     // 131072 int
#define W_WF      1048576u    // 1 MB: W packed as MFMA B-frags bf16 hi/lo
#define W_PART    2097152u    // NSPLIT x 4 MB f32 partials
#define PART_STRIDE 1048576ull

// round-to-nearest-even f32 -> bf16 bits
__device__ __forceinline__ unsigned short f2bf(float f) {
  unsigned u = __float_as_uint(f);
  return (unsigned short)((u + 0x7fffu + ((u >> 16) & 1u)) >> 16);
}

// device-scope grid barrier (all blocks co-resident: grid == 256 == #CUs)
__device__ __forceinline__ void gridbar(int* bar, int nblk) {
  __syncthreads();
  if (threadIdx.x == 0) {
    __threadfence();
    atomicAdd(bar, 1);
    while (__hip_atomic_load(bar, __ATOMIC_ACQUIRE, __HIP_MEMORY_SCOPE_AGENT) < nblk)
      __builtin_amdgcn_s_sleep(1);
  }
  __syncthreads();
}

// ---------------------------------------------------------------------------
// prep: pack W into MFMA B-frags (bf16 hi/lo) + zero counters/barriers.
// grid 128 x 256. Block kk packs k-chunk kk (32 k) for all 64 experts.
__global__ __launch_bounds__(256) void k_prep(const float* __restrict__ w,
                                              short8* __restrict__ wf,
                                              int* __restrict__ cq,
                                              int* __restrict__ gcount,
                                              int* __restrict__ bars) {
  const int kk   = blockIdx.x;
  const int nb   = threadIdx.x >> 6;
  const int lane = threadIdx.x & 63;
  const int n    = nb * 16 + (lane & 15);
  const int kb   = kk * 32 + (lane >> 4) * 8;
  const float4* wp = (const float4*)(w + (size_t)n * HID + kb);
  float4 f0 = wp[0], f1 = wp[1];
  float fv[8] = {f0.x, f0.y, f0.z, f0.w, f1.x, f1.y, f1.z, f1.w};
  short8 hi, lo;
#pragma unroll
  for (int j = 0; j < 8; ++j) {
    unsigned short h = f2bf(fv[j]);
    hi[j] = (short)h;
    float r = fv[j] - __uint_as_float((unsigned)h << 16);
    lo[j] = (short)f2bf(r);
  }
  size_t base = ((size_t)(kk * 4 + nb) * 2) * 64 + lane;
  wf[base] = hi;
  wf[base + 64] = lo;
  if (blockIdx.x == 0) {
    cq[threadIdx.x] = 0;
    if (threadIdx.x == 0) { gcount[0] = 0; bars[0] = 0; bars[1] = 0; bars[2] = 0; }
  }
}

// ---------------------------------------------------------------------------
// MFMA router GEMM: 4-term bf16 Ozaki split, f32 accumulate. No LDS/barriers.
__global__ __launch_bounds__(256, 2) void k_gemm(const float* __restrict__ x,
                                                 const short8* __restrict__ wf,
                                                 float* __restrict__ part) {
  const int tid  = threadIdx.x;
  const int wv   = tid >> 6;
  const int lane = tid & 63;
  const int t0   = blockIdx.x * 64;
  const int k0   = blockIdx.y * KSZ;
  const int row  = t0 + wv * 16 + (lane & 15);

  const float* xp = x + (size_t)row * HID + k0 + (lane >> 4) * 8;
  const short8* wp = wf + ((size_t)(k0 >> 5) * 4 * 2) * 64 + lane;

  f32x4 acc[4] = {{0,0,0,0},{0,0,0,0},{0,0,0,0},{0,0,0,0}};

#pragma unroll 2
  for (int kk = 0; kk < (KSZ >> 5); ++kk) {
    const float4* xq = (const float4*)(xp + kk * 32);
    float4 f0 = xq[0], f1 = xq[1];
    const short8* wq = wp + (size_t)kk * 8 * 64;
    short8 bh0 = wq[0],   bl0 = wq[64];
    short8 bh1 = wq[128], bl1 = wq[192];
    short8 bh2 = wq[256], bl2 = wq[320];
    short8 bh3 = wq[384], bl3 = wq[448];

    float fv[8] = {f0.x, f0.y, f0.z, f0.w, f1.x, f1.y, f1.z, f1.w};
    short8 ah, al;
#pragma unroll
    for (int j = 0; j < 8; ++j) {
      unsigned short h = f2bf(fv[j]);
      ah[j] = (short)h;
      float r = fv[j] - __uint_as_float((unsigned)h << 16);
      al[j] = (short)f2bf(r);
    }
    acc[0] = __builtin_amdgcn_mfma_f32_16x16x32_bf16(al, bl0, acc[0], 0, 0, 0);
    acc[0] = __builtin_amdgcn_mfma_f32_16x16x32_bf16(ah, bl0, acc[0], 0, 0, 0);
    acc[0] = __builtin_amdgcn_mfma_f32_16x16x32_bf16(al, bh0, acc[0], 0, 0, 0);
    acc[0] = __builtin_amdgcn_mfma_f32_16x16x32_bf16(ah, bh0, acc[0], 0, 0, 0);
    acc[1] = __builtin_amdgcn_mfma_f32_16x16x32_bf16(al, bl1, acc[1], 0, 0, 0);
    acc[1] = __builtin_amdgcn_mfma_f32_16x16x32_bf16(ah, bl1, acc[1], 0, 0, 0);
    acc[1] = __builtin_amdgcn_mfma_f32_16x16x32_bf16(al, bh1, acc[1], 0, 0, 0);
    acc[1] = __builtin_amdgcn_mfma_f32_16x16x32_bf16(ah, bh1, acc[1], 0, 0, 0);
    acc[2] = __builtin_amdgcn_mfma_f32_16x16x32_bf16(al, bl2, acc[2], 0, 0, 0);
    acc[2] = __builtin_amdgcn_mfma_f32_16x16x32_bf16(ah, bl2, acc[2], 0, 0, 0);
    acc[2] = __builtin_amdgcn_mfma_f32_16x16x32_bf16(al, bh2, acc[2], 0, 0, 0);
    acc[2] = __builtin_amdgcn_mfma_f32_16x16x32_bf16(ah, bh2, acc[2], 0, 0, 0);
    acc[3] = __builtin_amdgcn_mfma_f32_16x16x32_bf16(al, bl3, acc[3], 0, 0, 0);
    acc[3] = __builtin_amdgcn_mfma_f32_16x16x32_bf16(ah, bl3, acc[3], 0, 0, 0);
    acc[3] = __builtin_amdgcn_mfma_f32_16x16x32_bf16(al, bh3, acc[3], 0, 0, 0);
    acc[3] = __builtin_amdgcn_mfma_f32_16x16x32_bf16(ah, bh3, acc[3], 0, 0, 0);
  }

  float* p = part + (size_t)blockIdx.y * PART_STRIDE;
  const int mrow = t0 + wv * 16 + (lane >> 4) * 4;
  const int col  = lane & 15;
#pragma unroll
  for (int nb = 0; nb < 4; ++nb)
#pragma unroll
    for (int r = 0; r < 4; ++r)
      p[(size_t)(mrow + r) * 64 + nb * 16 + col] = acc[nb][r];
}

// ---------------------------------------------------------------------------
// Persistent fused tail: reduce+rowwise | repair | final | dispatch.
// grid EXACTLY 256 blocks x 256 threads (1 block/CU, all co-resident).
__global__ __launch_bounds__(256) void k_tail(const float* __restrict__ part,
                                              const float* __restrict__ x,
                                              const float* __restrict__ w,
                                              float* __restrict__ out,
                                              int* __restrict__ cq,
                                              int* __restrict__ gcount,
                                              int* __restrict__ bars,
                                              int* __restrict__ offs2,
                                              float* __restrict__ lsqp,
                                              float* __restrict__ psum,
                                              int* __restrict__ list,
                                              int* __restrict__ flat) {
  __shared__ float tile[64][68];
  __shared__ float invv[64];
  __shared__ int   hist[64];
  __shared__ int   wcs[4];
  __shared__ double shd[4][64];
  __shared__ double totd[64];
  const int bid = blockIdx.x;
  const int tid = threadIdx.x;

  // ---- Phase A: split-K reduce -> logits + per-row topk/flag/softmax ----
  if (tid < 64) hist[tid] = 0;
  {
    const size_t boff = (size_t)bid * 4096;
#pragma unroll
    for (int k = 0; k < 16; ++k) {
      int idx = k * 256 + tid;
      float v = part[boff + idx];
#pragma unroll
      for (int s = 1; s < NSPLIT; ++s) v += part[(size_t)s * PART_STRIDE + boff + idx];
      tile[idx >> 6][idx & 63] = v;
      out[O_LOGITS + boff + idx] = v;
    }
  }
  __syncthreads();

  if (tid < 64) {
    const unsigned t = bid * 64u + tid;
    float lv[64];
#pragma unroll
    for (int c = 0; c < 16; ++c) {
      float4 f = *(const float4*)&tile[tid][c * 4];
      lv[c * 4] = f.x; lv[c * 4 + 1] = f.y; lv[c * 4 + 2] = f.z; lv[c * 4 + 3] = f.w;
    }
    float val[9]; int idx[9];
#pragma unroll
    for (int j = 0; j < 9; ++j) { val[j] = -3.0e38f; idx[j] = 0; }
    float rm = -3.0e38f;
    bool flag = false;
#pragma unroll
    for (int e = 0; e < 64; ++e) {
      float v = lv[e];
      rm = fmaxf(rm, v);
      flag = flag || (fabsf(fabsf(v) - 2.0f) < EPS);
      float c = fminf(fmaxf(v, -2.0f), 2.0f);
      int id = e;
#pragma unroll
      for (int j = 0; j < 9; ++j) {
        bool sw = c > val[j];
        float tv = sw ? val[j] : c; int ti = sw ? idx[j] : id;
        val[j] = sw ? c : val[j];   idx[j] = sw ? id : idx[j];
        c = tv; id = ti;
      }
    }
#pragma unroll
    for (int j = 0; j < 8; ++j) {
      float gap = val[j] - val[j + 1];
      bool bothclip = (val[j] == val[j + 1]) && (fabsf(val[j]) == 2.0f);
      flag = flag || (gap < EPS && !bothclip);
    }
    if (!flag) {
      float m = val[0], pe[8], sum = 0.0f;
#pragma unroll
      for (int j = 0; j < 8; ++j) { pe[j] = expf(val[j] - m); sum += pe[j]; }
      float inv = 1.0f / sum;
#pragma unroll
      for (int j = 0; j < 8; ++j) {
        out[O_PROBS + (size_t)t * 8 + j] = pe[j] * inv;
        out[O_TIDX  + (size_t)t * 8 + j] = (float)idx[j];
        flat[(size_t)t * 8 + j] = idx[j];
        atomicAdd(&hist[idx[j]], 1);
      }
    } else {
      int sl = atomicAdd(gcount, 1);
      list[sl] = (int)t;
    }
    // full softmax denom; stash exp() in tile row for column-sum
    float se = 0.0f;
#pragma unroll
    for (int e = 0; e < 64; ++e) { float pv = expf(lv[e] - rm); tile[tid][e] = pv; se += pv; }
    invv[tid] = 1.0f / se;
    float lse = rm + logf(se);
    float l2 = lse * lse;
#pragma unroll
    for (int o = 32; o > 0; o >>= 1) l2 += __shfl_down(l2, o);
    if (tid == 0) lsqp[bid] = l2;
  }
  __syncthreads();
  if (tid < 64) {
    float s = 0.0f;
#pragma unroll
    for (int r = 0; r < 64; ++r) s += tile[r][tid] * invv[r];
    psum[(size_t)bid * 64 + tid] = s;
    atomicAdd(&cq[(bid >> 6) * 64 + tid], hist[tid]);
  }

  gridbar(&bars[0], 256);

  // ---- Phase B: exact f64 repair of flagged rows ----
  {
    const int n = *gcount;
    const int wave = tid >> 6, lane = tid & 63;
    for (int i = bid; i < n; i += 256) {
      const int row = list[i];
      const float* xr = x + (size_t)row * HID;
      const float* wr = w + (size_t)lane * HID;
      double p0 = 0.0, p1 = 0.0, p2 = 0.0, p3 = 0.0;
      const int kb = wave * 1024;
      for (int k = kb; k < kb + 1024; k += 4) {
        float4 xv = *(const float4*)&xr[k];
        float4 wv = *(const float4*)&wr[k];
        p0 = fma((double)xv.x, (double)wv.x, p0);
        p1 = fma((double)xv.y, (double)wv.y, p1);
        p2 = fma((double)xv.z, (double)wv.z, p2);
        p3 = fma((double)xv.w, (double)wv.w, p3);
      }
      shd[wave][lane] = (p0 + p1) + (p2 + p3);
      __syncthreads();
      if (wave == 0) totd[lane] = (shd[0][lane] + shd[1][lane]) + (shd[2][lane] + shd[3][lane]);
      __syncthreads();
      if (tid == 0) {
        double val[8]; int idx[8];
#pragma unroll
        for (int j = 0; j < 8; ++j) { val[j] = -1.0e300; idx[j] = 0; }
        for (int e = 0; e < 64; ++e) {
          double c = fmin(fmax(totd[e], -2.0), 2.0);
          int id = e;
#pragma unroll
          for (int j = 0; j < 8; ++j) {
            bool sw = c > val[j];
            double tv = sw ? val[j] : c; int ti = sw ? idx[j] : id;
            val[j] = sw ? c : val[j];    idx[j] = sw ? id : idx[j];
            c = tv; id = ti;
          }
        }
        float m = (float)val[0], pe[8], sum = 0.0f;
#pragma unroll
        for (int j = 0; j < 8; ++j) { pe[j] = expf((float)val[j] - m); sum += pe[j]; }
        float inv = 1.0f / sum;
        const int q = row >> 12;
#pragma unroll
        for (int j = 0; j < 8; ++j) {
          out[O_PROBS + (size_t)row * 8 + j] = pe[j] * inv;
          out[O_TIDX  + (size_t)row * 8 + j] = (float)idx[j];
          flat[(size_t)row * 8 + j] = idx[j];
          atomicAdd(&cq[q * 64 + idx[j]], 1);
        }
      }
      __syncthreads();
    }
  }

  gridbar(&bars[1], 256);

  // ---- Phase C: cumsum/offsets/losses (block 0, wave 0) ----
  if (bid == 0 && tid < 64) {
    const int e = tid;
    int tpe = cq[e] + cq[64 + e] + cq[128 + e] + cq[192 + e];
    tile[0][e] = __int_as_float(tpe);   // reuse LDS
    __builtin_amdgcn_wave_barrier();
    // wave-wide inclusive scan via LDS (single wave, no sync needed beyond barrier)
    int incl = 0;
    for (int i = 0; i <= e; ++i) incl += __float_as_int(tile[0][i]);
    out[O_TPE + e]   = (float)tpe;
    out[O_GROUP + e] = (float)incl;
    int o = incl - tpe;
#pragma unroll
    for (int q = 0; q < 4; ++q) { offs2[e * 4 + q] = o; o += cq[q * 64 + e]; }
    float ps = 0.0f;
    for (int b = 0; b < 256; ++b) ps += psum[b * 64 + e];
    float term = ((float)tpe / 131072.0f) * (ps / 16384.0f) * 64.0f;
#pragma unroll
    for (int o2 = 32; o2 > 0; o2 >>= 1) term += __shfl_down(term, o2);
    float zs = lsqp[e * 4] + lsqp[e * 4 + 1] + lsqp[e * 4 + 2] + lsqp[e * 4 + 3];
#pragma unroll
    for (int o2 = 32; o2 > 0; o2 >>= 1) zs += __shfl_down(zs, o2);
    if (e == 0) { out[O_LB] = term; out[O_ZL] = zs / 16384.0f; }
  }

  gridbar(&bars[2], 256);

  // ---- Phase D: stable counting-sort scatter, unit = (expert, quarter) ----
  {
    const int e = bid >> 2;
    const int q = bid & 3;
    const int lane = tid & 63;
    const int wv = tid >> 6;
    int base = offs2[e * 4 + q];
    const int seg0 = q * 32768;
    for (int c0 = 0; c0 < 32768; c0 += 2048) {
      const int j0 = seg0 + c0 + tid * 8;
      const int4* f4 = reinterpret_cast<const int4*>(flat + j0);
      int4 a = f4[0], b = f4[1];
      int v[8] = {a.x, a.y, a.z, a.w, b.x, b.y, b.z, b.w};
      int mcnt = 0;
#pragma unroll
      for (int k = 0; k < 8; ++k) mcnt += (v[k] == e) ? 1 : 0;
      int sc = mcnt;
#pragma unroll
      for (int o = 1; o < 64; o <<= 1) {
        int nn = __shfl_up(sc, o);
        if (lane >= o) sc += nn;
      }
      int excl = sc - mcnt;
      if (lane == 63) wcs[wv] = sc;
      __syncthreads();
      int woff = 0, tot = 0;
#pragma unroll
      for (int i = 0; i < 4; ++i) { int ci = wcs[i]; woff += (i < wv) ? ci : 0; tot += ci; }
      int pos = base + woff + excl;
#pragma unroll
      for (int k = 0; k < 8; ++k) {
        if (v[k] == e) { out[O_IDX + pos] = (float)(j0 + k); pos++; }
      }
      base += tot;
      __syncthreads();
    }
  }
}

// ---------------------------------------------------------------------------
extern "C" void kernel_launch(void* const* d_in, const int* in_sizes, int n_in,
                              void* d_out, int out_size, void* d_ws, size_t ws_size,
                              hipStream_t stream) {
  (void)in_sizes; (void)n_in; (void)out_size; (void)ws_size;
  const float* x  = (const float*)d_in[0];
  const float* Wm = (const float*)d_in[1];
  float* out = (float*)d_out;
  char*  ws  = (char*)d_ws;

  int*    cq     = (int*)(ws + W_CQ);
  int*    gcount = (int*)(ws + W_GCOUNT);
  int*    bars   = (int*)(ws + W_BARS);
  int*    offs2  = (int*)(ws + W_OFFS2);
  float*  lsqp   = (float*)(ws + W_LSQP);
  int*    list   = (int*)(ws + W_LIST);
  float*  psum   = (float*)(ws + W_PSUM);
  int*    flat   = (int*)(ws + W_FLAT);
  short8* wf     = (short8*)(ws + W_WF);
  float*  part   = (float*)(ws + W_PART);

  k_prep<<<dim3(128), dim3(256), 0, stream>>>(Wm, wf, cq, gcount, bars);
  k_gemm<<<dim3(NTOK / 64, NSPLIT), dim3(256), 0, stream>>>(x, wf, part);
  k_tail<<<dim3(256), dim3(256), 0, stream>>>(part, x, Wm, out, cq, gcount, bars,
                                              offs2, lsqp, psum, list, flat);
}

// Round 5
// 231.588 us; speedup vs baseline: 1.5863x; 1.5863x over previous
//
#include <hip/hip_runtime.h>
#include <hip/hip_bf16.h>
#include <math.h>

#define NTOK   16384
#define NEXP   64
#define HID    4096
#define KSEL   8
#define EPS    7.5e-5f

typedef __attribute__((ext_vector_type(8))) short short8;
typedef __attribute__((ext_vector_type(4))) float f32x4;

// d_out element offsets (f32 elements; int outputs stored as float values)
#define O_LOGITS 0u
#define O_PROBS  1048576u
#define O_TIDX   1179648u
#define O_GROUP  1310720u
#define O_IDX    1310784u
#define O_TPE    1441856u
#define O_LB     1441920u
#define O_ZL     1441921u

// ws byte offsets
#define W_CQ      0u          // 512 int: counts[q][e], q = row>>11 (8 segments)
#define W_GCOUNT  2048u       // 1 int
#define W_OFFS2   4096u       // 512 int: offsets[e][q]
#define W_LSQP    8192u       // 256 f32 per-block z-loss partials
#define W_LIST    16384u      // 16384 int flagged rows
#define W_PSUM    81920u      // 256*128 f32 per-block half-tile probsum partials
#define W_FLAT    262144u     // 131072 int
#define W_WF      1048576u    // 1 MB: W packed as MFMA B-frags bf16 hi/lo

// round-to-nearest-even f32 -> bf16 bits
__device__ __forceinline__ unsigned short f2bf(float f) {
  unsigned u = __float_as_uint(f);
  return (unsigned short)((u + 0x7fffu + ((u >> 16) & 1u)) >> 16);
}

// ---------------------------------------------------------------------------
// prep: pack W into MFMA B-frags (bf16 hi/lo) + zero counters.
// grid 128 x 256. Block kk packs k-chunk kk (32 k) for all 64 experts.
__global__ __launch_bounds__(256) void k_prep(const float* __restrict__ w,
                                              short8* __restrict__ wf,
                                              int* __restrict__ cq,
                                              int* __restrict__ gcount) {
  const int kk   = blockIdx.x;
  const int nb   = threadIdx.x >> 6;
  const int lane = threadIdx.x & 63;
  const int n    = nb * 16 + (lane & 15);
  const int kb   = kk * 32 + (lane >> 4) * 8;
  const float4* wp = (const float4*)(w + (size_t)n * HID + kb);
  float4 f0 = wp[0], f1 = wp[1];
  float fv[8] = {f0.x, f0.y, f0.z, f0.w, f1.x, f1.y, f1.z, f1.w};
  short8 hi, lo;
#pragma unroll
  for (int j = 0; j < 8; ++j) {
    unsigned short h = f2bf(fv[j]);
    hi[j] = (short)h;
    float r = fv[j] - __uint_as_float((unsigned)h << 16);
    lo[j] = (short)f2bf(r);
  }
  size_t base = ((size_t)(kk * 4 + nb) * 2) * 64 + lane;
  wf[base] = hi;
  wf[base + 64] = lo;
  if (blockIdx.x == 0) {
    cq[threadIdx.x] = 0;
    cq[threadIdx.x + 256] = 0;
    if (threadIdx.x == 0) gcount[0] = 0;
  }
}

// ---------------------------------------------------------------------------
// Fused GEMM + rowwise. Block = 64 tokens x 64 experts x K=4096.
// 512 thr = 8 waves: wave (ws, kh) = row-group ws (16 rows), K-half kh.
// 4-term bf16 Ozaki MFMA, f32 accumulate; LDS reduce of K-halves; then
// rowwise (topk/flag/softmax/losses) on the LDS logit tile.
__global__ __launch_bounds__(512, 4) void k_fused(const float* __restrict__ x,
                                                  const short8* __restrict__ wf,
                                                  float* __restrict__ out,
                                                  int* __restrict__ cq,
                                                  float* __restrict__ psum,
                                                  float* __restrict__ lsqp,
                                                  int* __restrict__ gcount,
                                                  int* __restrict__ list,
                                                  int* __restrict__ flat) {
  __shared__ float tile[64][68];
  __shared__ float red[4][64][20];
  __shared__ float rmv[64], invv[64];
  __shared__ int   hist[64];
  const int bid  = blockIdx.x;
  const int tid  = threadIdx.x;
  const int wv   = tid >> 6;
  const int lane = tid & 63;
  const int ws   = wv & 3;       // row group
  const int kh   = wv >> 2;      // K half
  const int t0   = bid * 64;

  if (tid < 64) hist[tid] = 0;

  // ---- GEMM: rows t0 + ws*16 .. +16, K-range kh*2048 .. +2048 ----
  const int row = t0 + ws * 16 + (lane & 15);
  const float* xp  = x + (size_t)row * HID + kh * 2048 + (lane >> 4) * 8;
  const short8* wp = wf + ((size_t)(kh * 64) * 8) * 64 + lane;

  f32x4 acc[4] = {{0,0,0,0},{0,0,0,0},{0,0,0,0},{0,0,0,0}};
#pragma unroll 2
  for (int kk = 0; kk < 64; ++kk) {
    const float4* xq = (const float4*)(xp + kk * 32);
    float4 f0 = xq[0], f1 = xq[1];
    const short8* wq = wp + (size_t)kk * 8 * 64;
    short8 bh0 = wq[0],   bl0 = wq[64];
    short8 bh1 = wq[128], bl1 = wq[192];
    short8 bh2 = wq[256], bl2 = wq[320];
    short8 bh3 = wq[384], bl3 = wq[448];

    float fv[8] = {f0.x, f0.y, f0.z, f0.w, f1.x, f1.y, f1.z, f1.w};
    short8 ah, al;
#pragma unroll
    for (int j = 0; j < 8; ++j) {
      unsigned short h = f2bf(fv[j]);
      ah[j] = (short)h;
      float r = fv[j] - __uint_as_float((unsigned)h << 16);
      al[j] = (short)f2bf(r);
    }
    acc[0] = __builtin_amdgcn_mfma_f32_16x16x32_bf16(al, bl0, acc[0], 0, 0, 0);
    acc[0] = __builtin_amdgcn_mfma_f32_16x16x32_bf16(ah, bl0, acc[0], 0, 0, 0);
    acc[0] = __builtin_amdgcn_mfma_f32_16x16x32_bf16(al, bh0, acc[0], 0, 0, 0);
    acc[0] = __builtin_amdgcn_mfma_f32_16x16x32_bf16(ah, bh0, acc[0], 0, 0, 0);
    acc[1] = __builtin_amdgcn_mfma_f32_16x16x32_bf16(al, bl1, acc[1], 0, 0, 0);
    acc[1] = __builtin_amdgcn_mfma_f32_16x16x32_bf16(ah, bl1, acc[1], 0, 0, 0);
    acc[1] = __builtin_amdgcn_mfma_f32_16x16x32_bf16(al, bh1, acc[1], 0, 0, 0);
    acc[1] = __builtin_amdgcn_mfma_f32_16x16x32_bf16(ah, bh1, acc[1], 0, 0, 0);
    acc[2] = __builtin_amdgcn_mfma_f32_16x16x32_bf16(al, bl2, acc[2], 0, 0, 0);
    acc[2] = __builtin_amdgcn_mfma_f32_16x16x32_bf16(ah, bl2, acc[2], 0, 0, 0);
    acc[2] = __builtin_amdgcn_mfma_f32_16x16x32_bf16(al, bh2, acc[2], 0, 0, 0);
    acc[2] = __builtin_amdgcn_mfma_f32_16x16x32_bf16(ah, bh2, acc[2], 0, 0, 0);
    acc[3] = __builtin_amdgcn_mfma_f32_16x16x32_bf16(al, bl3, acc[3], 0, 0, 0);
    acc[3] = __builtin_amdgcn_mfma_f32_16x16x32_bf16(ah, bl3, acc[3], 0, 0, 0);
    acc[3] = __builtin_amdgcn_mfma_f32_16x16x32_bf16(al, bh3, acc[3], 0, 0, 0);
    acc[3] = __builtin_amdgcn_mfma_f32_16x16x32_bf16(ah, bh3, acc[3], 0, 0, 0);
  }

  // ---- reduce K-halves via LDS; scatter D-frags into logit tile ----
  if (kh == 1) {
#pragma unroll
    for (int nb = 0; nb < 4; ++nb)
      *(float4*)&red[ws][lane][nb * 4] = make_float4(acc[nb][0], acc[nb][1], acc[nb][2], acc[nb][3]);
  }
  __syncthreads();
  if (kh == 0) {
    const int r0 = ws * 16 + (lane >> 4) * 4;
    const int c  = lane & 15;
#pragma unroll
    for (int nb = 0; nb < 4; ++nb) {
      float4 r = *(float4*)&red[ws][lane][nb * 4];
      acc[nb][0] += r.x; acc[nb][1] += r.y; acc[nb][2] += r.z; acc[nb][3] += r.w;
#pragma unroll
      for (int j = 0; j < 4; ++j) tile[r0 + j][nb * 16 + c] = acc[nb][j];
    }
  }
  __syncthreads();

  // ---- logits to global (coalesced from tile) ----
  {
    const size_t boff = (size_t)bid * 4096;
    const int r = tid >> 3, c = (tid & 7) * 8;
    float4 a = *(float4*)&tile[r][c], b = *(float4*)&tile[r][c + 4];
    *(float4*)&out[O_LOGITS + boff + r * 64 + c]     = a;
    *(float4*)&out[O_LOGITS + boff + r * 64 + c + 4] = b;
  }

  // ---- wave 1: per-row max, softmax denom, z-loss ----
  if (wv == 1) {
    const int r = lane;
    float rm = -3.0e38f;
#pragma unroll
    for (int c4 = 0; c4 < 16; ++c4) {
      float4 f = *(float4*)&tile[r][c4 * 4];
      rm = fmaxf(rm, fmaxf(fmaxf(f.x, f.y), fmaxf(f.z, f.w)));
    }
    float se = 0.0f;
#pragma unroll
    for (int c4 = 0; c4 < 16; ++c4) {
      float4 f = *(float4*)&tile[r][c4 * 4];
      se += expf(f.x - rm) + expf(f.y - rm) + expf(f.z - rm) + expf(f.w - rm);
    }
    rmv[r] = rm; invv[r] = 1.0f / se;
    float lse = rm + logf(se);
    float l2 = lse * lse;
#pragma unroll
    for (int o = 32; o > 0; o >>= 1) l2 += __shfl_down(l2, o);
    if (lane == 0) lsqp[bid] = l2;
  }
  __syncthreads();

  if (wv == 0) {
    // ---- top-9 stable insertion on clipped keys + flag near-ties ----
    const unsigned t = t0 + lane;
    float val[9]; int idx[9];
#pragma unroll
    for (int j = 0; j < 9; ++j) { val[j] = -3.0e38f; idx[j] = 0; }
    bool flag = false;
#pragma unroll
    for (int c4 = 0; c4 < 16; ++c4) {
      float4 f = *(float4*)&tile[lane][c4 * 4];
      float fe[4] = {f.x, f.y, f.z, f.w};
#pragma unroll
      for (int jj = 0; jj < 4; ++jj) {
        float v = fe[jj];
        flag = flag || (fabsf(fabsf(v) - 2.0f) < EPS);
        float c = fminf(fmaxf(v, -2.0f), 2.0f);
        int id = c4 * 4 + jj;
#pragma unroll
        for (int j = 0; j < 9; ++j) {
          bool sw = c > val[j];
          float tv = sw ? val[j] : c; int ti = sw ? idx[j] : id;
          val[j] = sw ? c : val[j];   idx[j] = sw ? id : idx[j];
          c = tv; id = ti;
        }
      }
    }
#pragma unroll
    for (int j = 0; j < 8; ++j) {
      float gap = val[j] - val[j + 1];
      bool bothclip = (val[j] == val[j + 1]) && (fabsf(val[j]) == 2.0f);
      flag = flag || (gap < EPS && !bothclip);
    }
    if (!flag) {
      float m = val[0], pe[8], sum = 0.0f;
#pragma unroll
      for (int j = 0; j < 8; ++j) { pe[j] = expf(val[j] - m); sum += pe[j]; }
      float inv = 1.0f / sum;
      *(float4*)&out[O_PROBS + (size_t)t * 8]     = make_float4(pe[0]*inv, pe[1]*inv, pe[2]*inv, pe[3]*inv);
      *(float4*)&out[O_PROBS + (size_t)t * 8 + 4] = make_float4(pe[4]*inv, pe[5]*inv, pe[6]*inv, pe[7]*inv);
      *(float4*)&out[O_TIDX + (size_t)t * 8]      = make_float4((float)idx[0], (float)idx[1], (float)idx[2], (float)idx[3]);
      *(float4*)&out[O_TIDX + (size_t)t * 8 + 4]  = make_float4((float)idx[4], (float)idx[5], (float)idx[6], (float)idx[7]);
      *(int4*)&flat[(size_t)t * 8]     = make_int4(idx[0], idx[1], idx[2], idx[3]);
      *(int4*)&flat[(size_t)t * 8 + 4] = make_int4(idx[4], idx[5], idx[6], idx[7]);
#pragma unroll
      for (int j = 0; j < 8; ++j) atomicAdd(&hist[idx[j]], 1);
    } else {
      int sl = atomicAdd(gcount, 1);
      list[sl] = (int)t;
    }
  } else if (wv == 2 || wv == 3) {
    // ---- softmax column half-sums (deterministic per-block partials) ----
    const int e = lane, half = wv - 2;
    float s = 0.0f;
#pragma unroll
    for (int r = 0; r < 32; ++r) {
      int rr = half * 32 + r;
      s += expf(tile[rr][e] - rmv[rr]) * invv[rr];
    }
    psum[(size_t)bid * 128 + half * 64 + e] = s;
  }
  __syncthreads();
  if (tid < 64) atomicAdd(&cq[(bid >> 5) * 64 + tid], hist[tid]);
}

// ---------------------------------------------------------------------------
// Exact f64 repair of flagged rows.
__global__ __launch_bounds__(256) void k_repair(const float* __restrict__ x,
                                                const float* __restrict__ w,
                                                const int* __restrict__ list,
                                                const int* __restrict__ gcount,
                                                float* __restrict__ out,
                                                int* __restrict__ cq,
                                                int* __restrict__ flat) {
  __shared__ double sh[4][64];
  __shared__ double tot[64];
  const int tid = threadIdx.x;
  const int wave = tid >> 6, lane = tid & 63;
  const int n = *gcount;
  for (int i = blockIdx.x; i < n; i += 256) {
    const int row = list[i];
    const float* xr = x + (size_t)row * HID;
    const float* wr = w + (size_t)lane * HID;
    double p0 = 0.0, p1 = 0.0, p2 = 0.0, p3 = 0.0;
    const int kb = wave * 1024;
    for (int k = kb; k < kb + 1024; k += 4) {
      float4 xv = *(const float4*)&xr[k];
      float4 wv = *(const float4*)&wr[k];
      p0 = fma((double)xv.x, (double)wv.x, p0);
      p1 = fma((double)xv.y, (double)wv.y, p1);
      p2 = fma((double)xv.z, (double)wv.z, p2);
      p3 = fma((double)xv.w, (double)wv.w, p3);
    }
    sh[wave][lane] = (p0 + p1) + (p2 + p3);
    __syncthreads();
    if (wave == 0) tot[lane] = (sh[0][lane] + sh[1][lane]) + (sh[2][lane] + sh[3][lane]);
    __syncthreads();
    if (tid == 0) {
      double val[8]; int idx[8];
#pragma unroll
      for (int j = 0; j < 8; ++j) { val[j] = -1.0e300; idx[j] = 0; }
      for (int e = 0; e < 64; ++e) {
        double c = fmin(fmax(tot[e], -2.0), 2.0);
        int id = e;
#pragma unroll
        for (int j = 0; j < 8; ++j) {
          bool sw = c > val[j];
          double tv = sw ? val[j] : c; int ti = sw ? idx[j] : id;
          val[j] = sw ? c : val[j];    idx[j] = sw ? id : idx[j];
          c = tv; id = ti;
        }
      }
      float m = (float)val[0], pe[8], sum = 0.0f;
#pragma unroll
      for (int j = 0; j < 8; ++j) { pe[j] = expf((float)val[j] - m); sum += pe[j]; }
      float inv = 1.0f / sum;
      const int q = row >> 11;
#pragma unroll
      for (int j = 0; j < 8; ++j) {
        out[O_PROBS + (size_t)row * 8 + j] = pe[j] * inv;
        out[O_TIDX  + (size_t)row * 8 + j] = (float)idx[j];
        flat[(size_t)row * 8 + j] = idx[j];
        atomicAdd(&cq[q * 64 + idx[j]], 1);
      }
    }
    __syncthreads();
  }
}

// ---------------------------------------------------------------------------
// cumsum/offsets + lb/z losses. 1 block x 256 threads.
__global__ __launch_bounds__(256) void k_final(const int* __restrict__ cq,
                                               const float* __restrict__ psum,
                                               const float* __restrict__ lsqp,
                                               float* __restrict__ out,
                                               int* __restrict__ offs2) {
  __shared__ int   ctot[64];
  __shared__ float gsum[4][64];
  const int tid = threadIdx.x;
  const int e = tid & 63, g = tid >> 6;

  if (tid < 64) {
    int tpe = 0;
#pragma unroll
    for (int q = 0; q < 8; ++q) tpe += cq[q * 64 + tid];
    ctot[tid] = tpe;
  }
  // lb partial sums (fixed order within each g-slice)
  float ps = 0.0f;
  for (int b = g; b < 256; b += 4) ps += psum[(size_t)b * 128 + e] + psum[(size_t)b * 128 + 64 + e];
  gsum[g][e] = ps;
  __syncthreads();

  if (tid < 64) {
    int incl = 0;
    for (int i = 0; i <= tid; ++i) incl += ctot[i];
    int tpe = ctot[tid];
    out[O_TPE + tid]   = (float)tpe;
    out[O_GROUP + tid] = (float)incl;
    int o = incl - tpe;
#pragma unroll
    for (int q = 0; q < 8; ++q) { offs2[tid * 8 + q] = o; o += cq[q * 64 + tid]; }

    float pst = (gsum[0][tid] + gsum[1][tid]) + (gsum[2][tid] + gsum[3][tid]);
    float term = ((float)tpe / 131072.0f) * (pst / 16384.0f) * 64.0f;
#pragma unroll
    for (int o2 = 32; o2 > 0; o2 >>= 1) term += __shfl_down(term, o2);
    float zs = (lsqp[tid * 4] + lsqp[tid * 4 + 1]) + (lsqp[tid * 4 + 2] + lsqp[tid * 4 + 3]);
#pragma unroll
    for (int o2 = 32; o2 > 0; o2 >>= 1) zs += __shfl_down(zs, o2);
    if (tid == 0) { out[O_LB] = term; out[O_ZL] = zs / 16384.0f; }
  }
}

// ---------------------------------------------------------------------------
// Stable counting-sort scatter, split 8x by row-eighth: 512 blocks.
__global__ __launch_bounds__(256) void k_dispatch(const int* __restrict__ flat,
                                                  const int* __restrict__ offs2,
                                                  float* __restrict__ out) {
  __shared__ int wcs[4];
  const int e = blockIdx.x >> 3;
  const int q = blockIdx.x & 7;
  const int tid = threadIdx.x;
  const int lane = tid & 63;
  const int wv = tid >> 6;
  int base = offs2[e * 8 + q];
  const int seg0 = q * 16384;
  for (int c0 = 0; c0 < 16384; c0 += 2048) {
    const int j0 = seg0 + c0 + tid * 8;
    const int4* f4 = reinterpret_cast<const int4*>(flat + j0);
    int4 a = f4[0], b = f4[1];
    int v[8] = {a.x, a.y, a.z, a.w, b.x, b.y, b.z, b.w};
    int mcnt = 0;
#pragma unroll
    for (int k = 0; k < 8; ++k) mcnt += (v[k] == e) ? 1 : 0;
    int sc = mcnt;
#pragma unroll
    for (int o = 1; o < 64; o <<= 1) {
      int nn = __shfl_up(sc, o);
      if (lane >= o) sc += nn;
    }
    int excl = sc - mcnt;
    if (lane == 63) wcs[wv] = sc;
    __syncthreads();
    int woff = 0, tot = 0;
#pragma unroll
    for (int i = 0; i < 4; ++i) { int ci = wcs[i]; woff += (i < wv) ? ci : 0; tot += ci; }
    int pos = base + woff + excl;
#pragma unroll
    for (int k = 0; k < 8; ++k) {
      if (v[k] == e) { out[O_IDX + pos] = (float)(j0 + k); pos++; }
    }
    base += tot;
    __syncthreads();
  }
}

// ---------------------------------------------------------------------------
extern "C" void kernel_launch(void* const* d_in, const int* in_sizes, int n_in,
                              void* d_out, int out_size, void* d_ws, size_t ws_size,
                              hipStream_t stream) {
  (void)in_sizes; (void)n_in; (void)out_size; (void)ws_size;
  const float* x  = (const float*)d_in[0];
  const float* Wm = (const float*)d_in[1];
  float* out = (float*)d_out;
  char*  ws  = (char*)d_ws;

  int*    cq     = (int*)(ws + W_CQ);
  int*    gcount = (int*)(ws + W_GCOUNT);
  int*    offs2  = (int*)(ws + W_OFFS2);
  float*  lsqp   = (float*)(ws + W_LSQP);
  int*    list   = (int*)(ws + W_LIST);
  float*  psum   = (float*)(ws + W_PSUM);
  int*    flat   = (int*)(ws + W_FLAT);
  short8* wf     = (short8*)(ws + W_WF);

  k_prep    <<<dim3(128), dim3(256), 0, stream>>>(Wm, wf, cq, gcount);
  k_fused   <<<dim3(256), dim3(512), 0, stream>>>(x, wf, out, cq, psum, lsqp, gcount, list, flat);
  k_repair  <<<dim3(256), dim3(256), 0, stream>>>(x, Wm, list, gcount, out, cq, flat);
  k_final   <<<dim3(1),   dim3(256), 0, stream>>>(cq, psum, lsqp, out, offs2);
  k_dispatch<<<dim3(512), dim3(256), 0, stream>>>(flat, offs2, out);
}

// Round 6
// 204.912 us; speedup vs baseline: 1.7928x; 1.1302x over previous
//
#include <hip/hip_runtime.h>
#include <hip/hip_bf16.h>
#include <math.h>

#define NTOK   16384
#define NEXP   64
#define HID    4096
#define KSEL   8
#define EPS    7.5e-5f
#define NSPLIT 4
#define KSZ    (HID / NSPLIT)

typedef __attribute__((ext_vector_type(8))) short short8;
typedef __attribute__((ext_vector_type(4))) float f32x4;

// d_out element offsets (f32 elements; int outputs stored as float values)
#define O_LOGITS 0u
#define O_PROBS  1048576u
#define O_TIDX   1179648u
#define O_GROUP  1310720u
#define O_IDX    1310784u
#define O_TPE    1441856u
#define O_LB     1441920u
#define O_ZL     1441921u

// ws byte offsets (proven budget: <= 18 MB)
#define W_CQ      0u          // 512 int: counts[q][e], q = row>>11
#define W_GCOUNT  2048u       // 1 int
#define W_OFFS2   4096u       // 512 int: offsets[e][q]
#define W_LSQP    8192u       // 256 f32 per-block z-loss partials
#define W_LIST    16384u      // 16384 int flagged rows
#define W_PSUM    81920u      // 256*128 f32 per-block half-tile probsum partials
#define W_FLAT    262144u     // 131072 int
#define W_WF      1048576u    // 1 MB: W packed as MFMA B-frags bf16 hi/lo
#define W_PART    2097152u    // NSPLIT x 4 MB f32 partials
#define PART_STRIDE 1048576ull

// round-to-nearest-even f32 -> bf16 bits
__device__ __forceinline__ unsigned short f2bf(float f) {
  unsigned u = __float_as_uint(f);
  return (unsigned short)((u + 0x7fffu + ((u >> 16) & 1u)) >> 16);
}

// ---------------------------------------------------------------------------
// prep: pack W into MFMA B-frags (bf16 hi/lo) + zero counters.
__global__ __launch_bounds__(256) void k_prep(const float* __restrict__ w,
                                              short8* __restrict__ wf,
                                              int* __restrict__ cq,
                                              int* __restrict__ gcount) {
  const int kk   = blockIdx.x;
  const int nb   = threadIdx.x >> 6;
  const int lane = threadIdx.x & 63;
  const int n    = nb * 16 + (lane & 15);
  const int kb   = kk * 32 + (lane >> 4) * 8;
  const float4* wp = (const float4*)(w + (size_t)n * HID + kb);
  float4 f0 = wp[0], f1 = wp[1];
  float fv[8] = {f0.x, f0.y, f0.z, f0.w, f1.x, f1.y, f1.z, f1.w};
  short8 hi, lo;
#pragma unroll
  for (int j = 0; j < 8; ++j) {
    unsigned short h = f2bf(fv[j]);
    hi[j] = (short)h;
    float r = fv[j] - __uint_as_float((unsigned)h << 16);
    lo[j] = (short)f2bf(r);
  }
  size_t base = ((size_t)(kk * 4 + nb) * 2) * 64 + lane;
  wf[base] = hi;
  wf[base + 64] = lo;
  if (blockIdx.x == 0) {
    cq[threadIdx.x] = 0;
    cq[threadIdx.x + 256] = 0;
    if (threadIdx.x == 0) gcount[0] = 0;
  }
}

// ---------------------------------------------------------------------------
// MFMA router GEMM: 4-term bf16 Ozaki split, f32 accumulate.
// Grid (256, NSPLIT) x 256 thr = 4 waves/block; wave = 16 rows x 64 experts.
// No LDS, no barriers; 16+ waves/CU for latency hiding.
__global__ __launch_bounds__(256, 4) void k_gemm(const float* __restrict__ x,
                                                 const short8* __restrict__ wf,
                                                 float* __restrict__ part) {
  const int tid  = threadIdx.x;
  const int wv   = tid >> 6;
  const int lane = tid & 63;
  const int t0   = blockIdx.x * 64;
  const int k0   = blockIdx.y * KSZ;
  const int row  = t0 + wv * 16 + (lane & 15);

  const float* xp = x + (size_t)row * HID + k0 + (lane >> 4) * 8;
  const short8* wp = wf + ((size_t)(k0 >> 5) * 4 * 2) * 64 + lane;

  f32x4 acc[4] = {{0,0,0,0},{0,0,0,0},{0,0,0,0},{0,0,0,0}};

#pragma unroll 2
  for (int kk = 0; kk < (KSZ >> 5); ++kk) {
    const float4* xq = (const float4*)(xp + kk * 32);
    float4 f0 = xq[0], f1 = xq[1];
    const short8* wq = wp + (size_t)kk * 8 * 64;
    short8 bh0 = wq[0],   bl0 = wq[64];
    short8 bh1 = wq[128], bl1 = wq[192];
    short8 bh2 = wq[256], bl2 = wq[320];
    short8 bh3 = wq[384], bl3 = wq[448];

    float fv[8] = {f0.x, f0.y, f0.z, f0.w, f1.x, f1.y, f1.z, f1.w};
    short8 ah, al;
#pragma unroll
    for (int j = 0; j < 8; ++j) {
      unsigned short h = f2bf(fv[j]);
      ah[j] = (short)h;
      float r = fv[j] - __uint_as_float((unsigned)h << 16);
      al[j] = (short)f2bf(r);
    }
    acc[0] = __builtin_amdgcn_mfma_f32_16x16x32_bf16(al, bl0, acc[0], 0, 0, 0);
    acc[0] = __builtin_amdgcn_mfma_f32_16x16x32_bf16(ah, bl0, acc[0], 0, 0, 0);
    acc[0] = __builtin_amdgcn_mfma_f32_16x16x32_bf16(al, bh0, acc[0], 0, 0, 0);
    acc[0] = __builtin_amdgcn_mfma_f32_16x16x32_bf16(ah, bh0, acc[0], 0, 0, 0);
    acc[1] = __builtin_amdgcn_mfma_f32_16x16x32_bf16(al, bl1, acc[1], 0, 0, 0);
    acc[1] = __builtin_amdgcn_mfma_f32_16x16x32_bf16(ah, bl1, acc[1], 0, 0, 0);
    acc[1] = __builtin_amdgcn_mfma_f32_16x16x32_bf16(al, bh1, acc[1], 0, 0, 0);
    acc[1] = __builtin_amdgcn_mfma_f32_16x16x32_bf16(ah, bh1, acc[1], 0, 0, 0);
    acc[2] = __builtin_amdgcn_mfma_f32_16x16x32_bf16(al, bl2, acc[2], 0, 0, 0);
    acc[2] = __builtin_amdgcn_mfma_f32_16x16x32_bf16(ah, bl2, acc[2], 0, 0, 0);
    acc[2] = __builtin_amdgcn_mfma_f32_16x16x32_bf16(al, bh2, acc[2], 0, 0, 0);
    acc[2] = __builtin_amdgcn_mfma_f32_16x16x32_bf16(ah, bh2, acc[2], 0, 0, 0);
    acc[3] = __builtin_amdgcn_mfma_f32_16x16x32_bf16(al, bl3, acc[3], 0, 0, 0);
    acc[3] = __builtin_amdgcn_mfma_f32_16x16x32_bf16(ah, bl3, acc[3], 0, 0, 0);
    acc[3] = __builtin_amdgcn_mfma_f32_16x16x32_bf16(al, bh3, acc[3], 0, 0, 0);
    acc[3] = __builtin_amdgcn_mfma_f32_16x16x32_bf16(ah, bh3, acc[3], 0, 0, 0);
  }

  float* p = part + (size_t)blockIdx.y * PART_STRIDE;
  const int mrow = t0 + wv * 16 + (lane >> 4) * 4;
  const int col  = lane & 15;
#pragma unroll
  for (int nb = 0; nb < 4; ++nb)
#pragma unroll
    for (int r = 0; r < 4; ++r)
      p[(size_t)(mrow + r) * 64 + nb * 16 + col] = acc[nb][r];
}

// ---------------------------------------------------------------------------
// Fused reduce + rowwise. 256 blocks x 256 thr (4 waves).
// Load: sum NSPLIT partials -> LDS tile + logits out.
// wave1: rowmax/denominator/z-loss; wave0: top-9/flag/topk-softmax/hist;
// waves2-3: softmax column half-sums.
__global__ __launch_bounds__(256) void k_rowtail(const float* __restrict__ part,
                                                 float* __restrict__ out,
                                                 int* __restrict__ cq,
                                                 float* __restrict__ psum,
                                                 float* __restrict__ lsqp,
                                                 int* __restrict__ gcount,
                                                 int* __restrict__ list,
                                                 int* __restrict__ flat) {
  __shared__ float tile[64][68];
  __shared__ float rmv[64], invv[64];
  __shared__ int   hist[64];
  const int bid  = blockIdx.x;
  const int tid  = threadIdx.x;
  const int wv   = tid >> 6;
  const int lane = tid & 63;
  const int t0   = bid * 64;
  if (tid < 64) hist[tid] = 0;

  {
    const size_t boff = (size_t)bid * 4096;
#pragma unroll
    for (int k = 0; k < 16; ++k) {
      int idx = k * 256 + tid;
      float v = part[boff + idx];
#pragma unroll
      for (int s = 1; s < NSPLIT; ++s) v += part[(size_t)s * PART_STRIDE + boff + idx];
      tile[idx >> 6][idx & 63] = v;
      out[O_LOGITS + boff + idx] = v;
    }
  }
  __syncthreads();

  // wave 1: per-row max, softmax denom, z-loss
  if (wv == 1) {
    const int r = lane;
    float rm = -3.0e38f;
#pragma unroll
    for (int c4 = 0; c4 < 16; ++c4) {
      float4 f = *(float4*)&tile[r][c4 * 4];
      rm = fmaxf(rm, fmaxf(fmaxf(f.x, f.y), fmaxf(f.z, f.w)));
    }
    float se = 0.0f;
#pragma unroll
    for (int c4 = 0; c4 < 16; ++c4) {
      float4 f = *(float4*)&tile[r][c4 * 4];
      se += expf(f.x - rm) + expf(f.y - rm) + expf(f.z - rm) + expf(f.w - rm);
    }
    rmv[r] = rm; invv[r] = 1.0f / se;
    float lse = rm + logf(se);
    float l2 = lse * lse;
#pragma unroll
    for (int o = 32; o > 0; o >>= 1) l2 += __shfl_down(l2, o);
    if (lane == 0) lsqp[bid] = l2;
  }
  __syncthreads();

  if (wv == 0) {
    // top-9 stable insertion on clipped keys + flag near-ties
    const unsigned t = t0 + lane;
    float val[9]; int idx[9];
#pragma unroll
    for (int j = 0; j < 9; ++j) { val[j] = -3.0e38f; idx[j] = 0; }
    bool flag = false;
#pragma unroll
    for (int c4 = 0; c4 < 16; ++c4) {
      float4 f = *(float4*)&tile[lane][c4 * 4];
      float fe[4] = {f.x, f.y, f.z, f.w};
#pragma unroll
      for (int jj = 0; jj < 4; ++jj) {
        float v = fe[jj];
        flag = flag || (fabsf(fabsf(v) - 2.0f) < EPS);
        float c = fminf(fmaxf(v, -2.0f), 2.0f);
        int id = c4 * 4 + jj;
#pragma unroll
        for (int j = 0; j < 9; ++j) {
          bool sw = c > val[j];
          float tv = sw ? val[j] : c; int ti = sw ? idx[j] : id;
          val[j] = sw ? c : val[j];   idx[j] = sw ? id : idx[j];
          c = tv; id = ti;
        }
      }
    }
#pragma unroll
    for (int j = 0; j < 8; ++j) {
      float gap = val[j] - val[j + 1];
      bool bothclip = (val[j] == val[j + 1]) && (fabsf(val[j]) == 2.0f);
      flag = flag || (gap < EPS && !bothclip);
    }
    if (!flag) {
      float m = val[0], pe[8], sum = 0.0f;
#pragma unroll
      for (int j = 0; j < 8; ++j) { pe[j] = expf(val[j] - m); sum += pe[j]; }
      float inv = 1.0f / sum;
      *(float4*)&out[O_PROBS + (size_t)t * 8]     = make_float4(pe[0]*inv, pe[1]*inv, pe[2]*inv, pe[3]*inv);
      *(float4*)&out[O_PROBS + (size_t)t * 8 + 4] = make_float4(pe[4]*inv, pe[5]*inv, pe[6]*inv, pe[7]*inv);
      *(float4*)&out[O_TIDX + (size_t)t * 8]      = make_float4((float)idx[0], (float)idx[1], (float)idx[2], (float)idx[3]);
      *(float4*)&out[O_TIDX + (size_t)t * 8 + 4]  = make_float4((float)idx[4], (float)idx[5], (float)idx[6], (float)idx[7]);
      *(int4*)&flat[(size_t)t * 8]     = make_int4(idx[0], idx[1], idx[2], idx[3]);
      *(int4*)&flat[(size_t)t * 8 + 4] = make_int4(idx[4], idx[5], idx[6], idx[7]);
#pragma unroll
      for (int j = 0; j < 8; ++j) atomicAdd(&hist[idx[j]], 1);
    } else {
      int sl = atomicAdd(gcount, 1);
      list[sl] = (int)t;
    }
  } else if (wv == 2 || wv == 3) {
    // softmax column half-sums (deterministic per-block partials)
    const int e = lane, half = wv - 2;
    float s = 0.0f;
#pragma unroll
    for (int r = 0; r < 32; ++r) {
      int rr = half * 32 + r;
      s += expf(tile[rr][e] - rmv[rr]) * invv[rr];
    }
    psum[(size_t)bid * 128 + half * 64 + e] = s;
  }
  __syncthreads();
  if (tid < 64) atomicAdd(&cq[(bid >> 5) * 64 + tid], hist[tid]);
}

// ---------------------------------------------------------------------------
// Exact f64 repair of flagged rows.
__global__ __launch_bounds__(256) void k_repair(const float* __restrict__ x,
                                                const float* __restrict__ w,
                                                const int* __restrict__ list,
                                                const int* __restrict__ gcount,
                                                float* __restrict__ out,
                                                int* __restrict__ cq,
                                                int* __restrict__ flat) {
  __shared__ double sh[4][64];
  __shared__ double tot[64];
  const int tid = threadIdx.x;
  const int wave = tid >> 6, lane = tid & 63;
  const int n = *gcount;
  for (int i = blockIdx.x; i < n; i += 256) {
    const int row = list[i];
    const float* xr = x + (size_t)row * HID;
    const float* wr = w + (size_t)lane * HID;
    double p0 = 0.0, p1 = 0.0, p2 = 0.0, p3 = 0.0;
    const int kb = wave * 1024;
    for (int k = kb; k < kb + 1024; k += 4) {
      float4 xv = *(const float4*)&xr[k];
      float4 wv = *(const float4*)&wr[k];
      p0 = fma((double)xv.x, (double)wv.x, p0);
      p1 = fma((double)xv.y, (double)wv.y, p1);
      p2 = fma((double)xv.z, (double)wv.z, p2);
      p3 = fma((double)xv.w, (double)wv.w, p3);
    }
    sh[wave][lane] = (p0 + p1) + (p2 + p3);
    __syncthreads();
    if (wave == 0) tot[lane] = (sh[0][lane] + sh[1][lane]) + (sh[2][lane] + sh[3][lane]);
    __syncthreads();
    if (tid == 0) {
      double val[8]; int idx[8];
#pragma unroll
      for (int j = 0; j < 8; ++j) { val[j] = -1.0e300; idx[j] = 0; }
      for (int e = 0; e < 64; ++e) {
        double c = fmin(fmax(tot[e], -2.0), 2.0);
        int id = e;
#pragma unroll
        for (int j = 0; j < 8; ++j) {
          bool sw = c > val[j];
          double tv = sw ? val[j] : c; int ti = sw ? idx[j] : id;
          val[j] = sw ? c : val[j];    idx[j] = sw ? id : idx[j];
          c = tv; id = ti;
        }
      }
      float m = (float)val[0], pe[8], sum = 0.0f;
#pragma unroll
      for (int j = 0; j < 8; ++j) { pe[j] = expf((float)val[j] - m); sum += pe[j]; }
      float inv = 1.0f / sum;
      const int q = row >> 11;
#pragma unroll
      for (int j = 0; j < 8; ++j) {
        out[O_PROBS + (size_t)row * 8 + j] = pe[j] * inv;
        out[O_TIDX  + (size_t)row * 8 + j] = (float)idx[j];
        flat[(size_t)row * 8 + j] = idx[j];
        atomicAdd(&cq[q * 64 + idx[j]], 1);
      }
    }
    __syncthreads();
  }
}

// ---------------------------------------------------------------------------
// cumsum/offsets + lb/z losses. 1 block x 256 threads.
__global__ __launch_bounds__(256) void k_final(const int* __restrict__ cq,
                                               const float* __restrict__ psum,
                                               const float* __restrict__ lsqp,
                                               float* __restrict__ out,
                                               int* __restrict__ offs2) {
  __shared__ int   ctot[64];
  __shared__ float gsum[4][64];
  const int tid = threadIdx.x;
  const int e = tid & 63, g = tid >> 6;

  if (tid < 64) {
    int tpe = 0;
#pragma unroll
    for (int q = 0; q < 8; ++q) tpe += cq[q * 64 + tid];
    ctot[tid] = tpe;
  }
  float ps = 0.0f;
  for (int b = g; b < 256; b += 4) ps += psum[(size_t)b * 128 + e] + psum[(size_t)b * 128 + 64 + e];
  gsum[g][e] = ps;
  __syncthreads();

  if (tid < 64) {
    int incl = 0;
    for (int i = 0; i <= tid; ++i) incl += ctot[i];
    int tpe = ctot[tid];
    out[O_TPE + tid]   = (float)tpe;
    out[O_GROUP + tid] = (float)incl;
    int o = incl - tpe;
#pragma unroll
    for (int q = 0; q < 8; ++q) { offs2[tid * 8 + q] = o; o += cq[q * 64 + tid]; }

    float pst = (gsum[0][tid] + gsum[1][tid]) + (gsum[2][tid] + gsum[3][tid]);
    float term = ((float)tpe / 131072.0f) * (pst / 16384.0f) * 64.0f;
#pragma unroll
    for (int o2 = 32; o2 > 0; o2 >>= 1) term += __shfl_down(term, o2);
    float zs = (lsqp[tid * 4] + lsqp[tid * 4 + 1]) + (lsqp[tid * 4 + 2] + lsqp[tid * 4 + 3]);
#pragma unroll
    for (int o2 = 32; o2 > 0; o2 >>= 1) zs += __shfl_down(zs, o2);
    if (tid == 0) { out[O_LB] = term; out[O_ZL] = zs / 16384.0f; }
  }
}

// ---------------------------------------------------------------------------
// Stable counting-sort scatter, split 8x by row-eighth: 512 blocks.
__global__ __launch_bounds__(256) void k_dispatch(const int* __restrict__ flat,
                                                  const int* __restrict__ offs2,
                                                  float* __restrict__ out) {
  __shared__ int wcs[4];
  const int e = blockIdx.x >> 3;
  const int q = blockIdx.x & 7;
  const int tid = threadIdx.x;
  const int lane = tid & 63;
  const int wv = tid >> 6;
  int base = offs2[e * 8 + q];
  const int seg0 = q * 16384;
  for (int c0 = 0; c0 < 16384; c0 += 2048) {
    const int j0 = seg0 + c0 + tid * 8;
    const int4* f4 = reinterpret_cast<const int4*>(flat + j0);
    int4 a = f4[0], b = f4[1];
    int v[8] = {a.x, a.y, a.z, a.w, b.x, b.y, b.z, b.w};
    int mcnt = 0;
#pragma unroll
    for (int k = 0; k < 8; ++k) mcnt += (v[k] == e) ? 1 : 0;
    int sc = mcnt;
#pragma unroll
    for (int o = 1; o < 64; o <<= 1) {
      int nn = __shfl_up(sc, o);
      if (lane >= o) sc += nn;
    }
    int excl = sc - mcnt;
    if (lane == 63) wcs[wv] = sc;
    __syncthreads();
    int woff = 0, tot = 0;
#pragma unroll
    for (int i = 0; i < 4; ++i) { int ci = wcs[i]; woff += (i < wv) ? ci : 0; tot += ci; }
    int pos = base + woff + excl;
#pragma unroll
    for (int k = 0; k < 8; ++k) {
      if (v[k] == e) { out[O_IDX + pos] = (float)(j0 + k); pos++; }
    }
    base += tot;
    __syncthreads();
  }
}

// ---------------------------------------------------------------------------
extern "C" void kernel_launch(void* const* d_in, const int* in_sizes, int n_in,
                              void* d_out, int out_size, void* d_ws, size_t ws_size,
                              hipStream_t stream) {
  (void)in_sizes; (void)n_in; (void)out_size; (void)ws_size;
  const float* x  = (const float*)d_in[0];
  const float* Wm = (const float*)d_in[1];
  float* out = (float*)d_out;
  char*  ws  = (char*)d_ws;

  int*    cq     = (int*)(ws + W_CQ);
  int*    gcount = (int*)(ws + W_GCOUNT);
  int*    offs2  = (int*)(ws + W_OFFS2);
  float*  lsqp   = (float*)(ws + W_LSQP);
  int*    list   = (int*)(ws + W_LIST);
  float*  psum   = (float*)(ws + W_PSUM);
  int*    flat   = (int*)(ws + W_FLAT);
  short8* wf     = (short8*)(ws + W_WF);
  float*  part   = (float*)(ws + W_PART);

  k_prep    <<<dim3(128), dim3(256), 0, stream>>>(Wm, wf, cq, gcount);
  k_gemm    <<<dim3(NTOK / 64, NSPLIT), dim3(256), 0, stream>>>(x, wf, part);
  k_rowtail <<<dim3(256), dim3(256), 0, stream>>>(part, out, cq, psum, lsqp, gcount, list, flat);
  k_repair  <<<dim3(256), dim3(256), 0, stream>>>(x, Wm, list, gcount, out, cq, flat);
  k_final   <<<dim3(1),   dim3(256), 0, stream>>>(cq, psum, lsqp, out, offs2);
  k_dispatch<<<dim3(512), dim3(256), 0, stream>>>(flat, offs2, out);
}

// Round 7
// 204.027 us; speedup vs baseline: 1.8006x; 1.0043x over previous
//
#include <hip/hip_runtime.h>
#include <hip/hip_bf16.h>
#include <math.h>

#define NTOK   16384
#define NEXP   64
#define HID    4096
#define KSEL   8
#define EPS    7.5e-5f
#define NSPLIT 8
#define KSZ    (HID / NSPLIT)

typedef __attribute__((ext_vector_type(8))) short short8;
typedef __attribute__((ext_vector_type(4))) float f32x4;

// d_out element offsets (f32 elements; int outputs stored as float values)
#define O_LOGITS 0u
#define O_PROBS  1048576u
#define O_TIDX   1179648u
#define O_GROUP  1310720u
#define O_IDX    1310784u
#define O_TPE    1441856u
#define O_LB     1441920u
#define O_ZL     1441921u

// ws byte offsets
#define W_CQ      0u          // 512 int: counts[q][e], q = row>>11
#define W_GCOUNT  2048u       // 1 int
#define W_OFFS2   4096u       // 512 int: offsets[e][q]
#define W_LSQP    8192u       // 256 f32 per-block z-loss partials
#define W_LIST    16384u      // 16384 int flagged rows
#define W_PSUM    81920u      // 256*128 f32 per-block half-tile probsum partials
#define W_FLAT    262144u     // 131072 int
#define W_WF      1048576u    // 1 MB: W packed as MFMA B-frags bf16 hi/lo
#define W_PART    2097152u    // NSPLIT x 4 MB f32 partials (32 MB)
#define PART_STRIDE 1048576ull

// round-to-nearest-even f32 -> bf16 bits
__device__ __forceinline__ unsigned short f2bf(float f) {
  unsigned u = __float_as_uint(f);
  return (unsigned short)((u + 0x7fffu + ((u >> 16) & 1u)) >> 16);
}

// ---------------------------------------------------------------------------
// prep: pack W into MFMA B-frags (bf16 hi/lo, RNE both) + zero counters.
__global__ __launch_bounds__(256) void k_prep(const float* __restrict__ w,
                                              short8* __restrict__ wf,
                                              int* __restrict__ cq,
                                              int* __restrict__ gcount) {
  const int kk   = blockIdx.x;
  const int nb   = threadIdx.x >> 6;
  const int lane = threadIdx.x & 63;
  const int n    = nb * 16 + (lane & 15);
  const int kb   = kk * 32 + (lane >> 4) * 8;
  const float4* wp = (const float4*)(w + (size_t)n * HID + kb);
  float4 f0 = wp[0], f1 = wp[1];
  float fv[8] = {f0.x, f0.y, f0.z, f0.w, f1.x, f1.y, f1.z, f1.w};
  short8 hi, lo;
#pragma unroll
  for (int j = 0; j < 8; ++j) {
    unsigned short h = f2bf(fv[j]);
    hi[j] = (short)h;
    float r = fv[j] - __uint_as_float((unsigned)h << 16);
    lo[j] = (short)f2bf(r);
  }
  size_t base = ((size_t)(kk * 4 + nb) * 2) * 64 + lane;
  wf[base] = hi;
  wf[base + 64] = lo;
  if (blockIdx.x == 0) {
    cq[threadIdx.x] = 0;
    cq[threadIdx.x + 256] = 0;
    if (threadIdx.x == 0) gcount[0] = 0;
  }
}

// ---------------------------------------------------------------------------
// MFMA router GEMM: 3-term bf16 Ozaki split (ah*bh + al*bh + ah*bl),
// ah = truncated bf16 (v_perm pack), al = RNE(residual). f32 accumulate.
// Grid (256, 8) x 256 thr; __launch_bounds__(256,8) -> VGPR<=64 ->
// 8 blocks/CU = 32 waves/CU for max latency hiding. No LDS, no barriers.
__global__ __launch_bounds__(256, 8) void k_gemm(const float* __restrict__ x,
                                                 const short8* __restrict__ wf,
                                                 float* __restrict__ part) {
  const int tid  = threadIdx.x;
  const int wv   = tid >> 6;
  const int lane = tid & 63;
  const int t0   = blockIdx.x * 64;
  const int k0   = blockIdx.y * KSZ;
  const int row  = t0 + wv * 16 + (lane & 15);

  const float* xp = x + (size_t)row * HID + k0 + (lane >> 4) * 8;
  const short8* wp = wf + ((size_t)(k0 >> 5) * 8) * 64 + lane;

  f32x4 acc[4] = {{0,0,0,0},{0,0,0,0},{0,0,0,0},{0,0,0,0}};

#pragma unroll 2
  for (int kk = 0; kk < (KSZ >> 5); ++kk) {
    const float4* xq = (const float4*)(xp + kk * 32);
    float4 f0 = xq[0], f1 = xq[1];
    unsigned xb[8] = {__float_as_uint(f0.x), __float_as_uint(f0.y),
                      __float_as_uint(f0.z), __float_as_uint(f0.w),
                      __float_as_uint(f1.x), __float_as_uint(f1.y),
                      __float_as_uint(f1.z), __float_as_uint(f1.w)};
    union { unsigned u[4]; short8 s; } ua, ul;
#pragma unroll
    for (int p = 0; p < 4; ++p) {
      unsigned b0 = xb[2 * p], b1 = xb[2 * p + 1];
      ua.u[p] = __builtin_amdgcn_perm(b1, b0, 0x07060302u);   // {trunc16(b0), trunc16(b1)}
      float r0 = __uint_as_float(b0) - __uint_as_float(b0 & 0xffff0000u);
      float r1 = __uint_as_float(b1) - __uint_as_float(b1 & 0xffff0000u);
      unsigned t0b = __float_as_uint(r0), t1b = __float_as_uint(r1);
      t0b += 0x7fffu + ((t0b >> 16) & 1u);                    // RNE round-up bits
      t1b += 0x7fffu + ((t1b >> 16) & 1u);
      ul.u[p] = __builtin_amdgcn_perm(t1b, t0b, 0x07060302u); // {rne16(r0), rne16(r1)}
    }
    short8 ah = ua.s, al = ul.s;
    const short8* wq = wp + (size_t)kk * 8 * 64;
#pragma unroll
    for (int nb = 0; nb < 4; ++nb) {
      short8 bh = wq[nb * 128];
      short8 bl = wq[nb * 128 + 64];
      acc[nb] = __builtin_amdgcn_mfma_f32_16x16x32_bf16(ah, bh, acc[nb], 0, 0, 0);
      acc[nb] = __builtin_amdgcn_mfma_f32_16x16x32_bf16(al, bh, acc[nb], 0, 0, 0);
      acc[nb] = __builtin_amdgcn_mfma_f32_16x16x32_bf16(ah, bl, acc[nb], 0, 0, 0);
    }
  }

  float* p = part + (size_t)blockIdx.y * PART_STRIDE;
  const int mrow = t0 + wv * 16 + (lane >> 4) * 4;
  const int col  = lane & 15;
#pragma unroll
  for (int nb = 0; nb < 4; ++nb)
#pragma unroll
    for (int r = 0; r < 4; ++r)
      p[(size_t)(mrow + r) * 64 + nb * 16 + col] = acc[nb][r];
}

// ---------------------------------------------------------------------------
// Fused reduce + rowwise. 256 blocks x 256 thr (4 waves).
__global__ __launch_bounds__(256) void k_rowtail(const float* __restrict__ part,
                                                 float* __restrict__ out,
                                                 int* __restrict__ cq,
                                                 float* __restrict__ psum,
                                                 float* __restrict__ lsqp,
                                                 int* __restrict__ gcount,
                                                 int* __restrict__ list,
                                                 int* __restrict__ flat) {
  __shared__ float tile[64][68];
  __shared__ float rmv[64], invv[64];
  __shared__ int   hist[64];
  const int bid  = blockIdx.x;
  const int tid  = threadIdx.x;
  const int wv   = tid >> 6;
  const int lane = tid & 63;
  const int t0   = bid * 64;
  if (tid < 64) hist[tid] = 0;

  {
    const size_t boff = (size_t)bid * 4096;
#pragma unroll
    for (int k = 0; k < 16; ++k) {
      int idx = k * 256 + tid;
      float v = part[boff + idx];
#pragma unroll
      for (int s = 1; s < NSPLIT; ++s) v += part[(size_t)s * PART_STRIDE + boff + idx];
      tile[idx >> 6][idx & 63] = v;
      out[O_LOGITS + boff + idx] = v;
    }
  }
  __syncthreads();

  // wave 1: per-row max, softmax denom, z-loss
  if (wv == 1) {
    const int r = lane;
    float rm = -3.0e38f;
#pragma unroll
    for (int c4 = 0; c4 < 16; ++c4) {
      float4 f = *(float4*)&tile[r][c4 * 4];
      rm = fmaxf(rm, fmaxf(fmaxf(f.x, f.y), fmaxf(f.z, f.w)));
    }
    float se = 0.0f;
#pragma unroll
    for (int c4 = 0; c4 < 16; ++c4) {
      float4 f = *(float4*)&tile[r][c4 * 4];
      se += expf(f.x - rm) + expf(f.y - rm) + expf(f.z - rm) + expf(f.w - rm);
    }
    rmv[r] = rm; invv[r] = 1.0f / se;
    float lse = rm + logf(se);
    float l2 = lse * lse;
#pragma unroll
    for (int o = 32; o > 0; o >>= 1) l2 += __shfl_down(l2, o);
    if (lane == 0) lsqp[bid] = l2;
  }
  __syncthreads();

  if (wv == 0) {
    // top-9 stable insertion on clipped keys + flag near-ties
    const unsigned t = t0 + lane;
    float val[9]; int idx[9];
#pragma unroll
    for (int j = 0; j < 9; ++j) { val[j] = -3.0e38f; idx[j] = 0; }
    bool flag = false;
#pragma unroll
    for (int c4 = 0; c4 < 16; ++c4) {
      float4 f = *(float4*)&tile[lane][c4 * 4];
      float fe[4] = {f.x, f.y, f.z, f.w};
#pragma unroll
      for (int jj = 0; jj < 4; ++jj) {
        float v = fe[jj];
        flag = flag || (fabsf(fabsf(v) - 2.0f) < EPS);
        float c = fminf(fmaxf(v, -2.0f), 2.0f);
        int id = c4 * 4 + jj;
#pragma unroll
        for (int j = 0; j < 9; ++j) {
          bool sw = c > val[j];
          float tv = sw ? val[j] : c; int ti = sw ? idx[j] : id;
          val[j] = sw ? c : val[j];   idx[j] = sw ? id : idx[j];
          c = tv; id = ti;
        }
      }
    }
#pragma unroll
    for (int j = 0; j < 8; ++j) {
      float gap = val[j] - val[j + 1];
      bool bothclip = (val[j] == val[j + 1]) && (fabsf(val[j]) == 2.0f);
      flag = flag || (gap < EPS && !bothclip);
    }
    if (!flag) {
      float m = val[0], pe[8], sum = 0.0f;
#pragma unroll
      for (int j = 0; j < 8; ++j) { pe[j] = expf(val[j] - m); sum += pe[j]; }
      float inv = 1.0f / sum;
      *(float4*)&out[O_PROBS + (size_t)t * 8]     = make_float4(pe[0]*inv, pe[1]*inv, pe[2]*inv, pe[3]*inv);
      *(float4*)&out[O_PROBS + (size_t)t * 8 + 4] = make_float4(pe[4]*inv, pe[5]*inv, pe[6]*inv, pe[7]*inv);
      *(float4*)&out[O_TIDX + (size_t)t * 8]      = make_float4((float)idx[0], (float)idx[1], (float)idx[2], (float)idx[3]);
      *(float4*)&out[O_TIDX + (size_t)t * 8 + 4]  = make_float4((float)idx[4], (float)idx[5], (float)idx[6], (float)idx[7]);
      *(int4*)&flat[(size_t)t * 8]     = make_int4(idx[0], idx[1], idx[2], idx[3]);
      *(int4*)&flat[(size_t)t * 8 + 4] = make_int4(idx[4], idx[5], idx[6], idx[7]);
#pragma unroll
      for (int j = 0; j < 8; ++j) atomicAdd(&hist[idx[j]], 1);
    } else {
      int sl = atomicAdd(gcount, 1);
      list[sl] = (int)t;
    }
  } else if (wv == 2 || wv == 3) {
    // softmax column half-sums (deterministic per-block partials)
    const int e = lane, half = wv - 2;
    float s = 0.0f;
#pragma unroll
    for (int r = 0; r < 32; ++r) {
      int rr = half * 32 + r;
      s += expf(tile[rr][e] - rmv[rr]) * invv[rr];
    }
    psum[(size_t)bid * 128 + half * 64 + e] = s;
  }
  __syncthreads();
  if (tid < 64) atomicAdd(&cq[(bid >> 5) * 64 + tid], hist[tid]);
}

// ---------------------------------------------------------------------------
// Exact f64 repair of flagged rows.
__global__ __launch_bounds__(256) void k_repair(const float* __restrict__ x,
                                                const float* __restrict__ w,
                                                const int* __restrict__ list,
                                                const int* __restrict__ gcount,
                                                float* __restrict__ out,
                                                int* __restrict__ cq,
                                                int* __restrict__ flat) {
  __shared__ double sh[4][64];
  __shared__ double tot[64];
  const int tid = threadIdx.x;
  const int wave = tid >> 6, lane = tid & 63;
  const int n = *gcount;
  for (int i = blockIdx.x; i < n; i += 256) {
    const int row = list[i];
    const float* xr = x + (size_t)row * HID;
    const float* wr = w + (size_t)lane * HID;
    double p0 = 0.0, p1 = 0.0, p2 = 0.0, p3 = 0.0;
    const int kb = wave * 1024;
    for (int k = kb; k < kb + 1024; k += 4) {
      float4 xv = *(const float4*)&xr[k];
      float4 wv = *(const float4*)&wr[k];
      p0 = fma((double)xv.x, (double)wv.x, p0);
      p1 = fma((double)xv.y, (double)wv.y, p1);
      p2 = fma((double)xv.z, (double)wv.z, p2);
      p3 = fma((double)xv.w, (double)wv.w, p3);
    }
    sh[wave][lane] = (p0 + p1) + (p2 + p3);
    __syncthreads();
    if (wave == 0) tot[lane] = (sh[0][lane] + sh[1][lane]) + (sh[2][lane] + sh[3][lane]);
    __syncthreads();
    if (tid == 0) {
      double val[8]; int idx[8];
#pragma unroll
      for (int j = 0; j < 8; ++j) { val[j] = -1.0e300; idx[j] = 0; }
      for (int e = 0; e < 64; ++e) {
        double c = fmin(fmax(tot[e], -2.0), 2.0);
        int id = e;
#pragma unroll
        for (int j = 0; j < 8; ++j) {
          bool sw = c > val[j];
          double tv = sw ? val[j] : c; int ti = sw ? idx[j] : id;
          val[j] = sw ? c : val[j];    idx[j] = sw ? id : idx[j];
          c = tv; id = ti;
        }
      }
      float m = (float)val[0], pe[8], sum = 0.0f;
#pragma unroll
      for (int j = 0; j < 8; ++j) { pe[j] = expf((float)val[j] - m); sum += pe[j]; }
      float inv = 1.0f / sum;
      const int q = row >> 11;
#pragma unroll
      for (int j = 0; j < 8; ++j) {
        out[O_PROBS + (size_t)row * 8 + j] = pe[j] * inv;
        out[O_TIDX  + (size_t)row * 8 + j] = (float)idx[j];
        flat[(size_t)row * 8 + j] = idx[j];
        atomicAdd(&cq[q * 64 + idx[j]], 1);
      }
    }
    __syncthreads();
  }
}

// ---------------------------------------------------------------------------
// cumsum/offsets + lb/z losses. 1 block x 256 threads.
__global__ __launch_bounds__(256) void k_final(const int* __restrict__ cq,
                                               const float* __restrict__ psum,
                                               const float* __restrict__ lsqp,
                                               float* __restrict__ out,
                                               int* __restrict__ offs2) {
  __shared__ int   ctot[64];
  __shared__ float gsum[4][64];
  const int tid = threadIdx.x;
  const int e = tid & 63, g = tid >> 6;

  if (tid < 64) {
    int tpe = 0;
#pragma unroll
    for (int q = 0; q < 8; ++q) tpe += cq[q * 64 + tid];
    ctot[tid] = tpe;
  }
  float ps = 0.0f;
  for (int b = g; b < 256; b += 4) ps += psum[(size_t)b * 128 + e] + psum[(size_t)b * 128 + 64 + e];
  gsum[g][e] = ps;
  __syncthreads();

  if (tid < 64) {
    int incl = 0;
    for (int i = 0; i <= tid; ++i) incl += ctot[i];
    int tpe = ctot[tid];
    out[O_TPE + tid]   = (float)tpe;
    out[O_GROUP + tid] = (float)incl;
    int o = incl - tpe;
#pragma unroll
    for (int q = 0; q < 8; ++q) { offs2[tid * 8 + q] = o; o += cq[q * 64 + tid]; }

    float pst = (gsum[0][tid] + gsum[1][tid]) + (gsum[2][tid] + gsum[3][tid]);
    float term = ((float)tpe / 131072.0f) * (pst / 16384.0f) * 64.0f;
#pragma unroll
    for (int o2 = 32; o2 > 0; o2 >>= 1) term += __shfl_down(term, o2);
    float zs = (lsqp[tid * 4] + lsqp[tid * 4 + 1]) + (lsqp[tid * 4 + 2] + lsqp[tid * 4 + 3]);
#pragma unroll
    for (int o2 = 32; o2 > 0; o2 >>= 1) zs += __shfl_down(zs, o2);
    if (tid == 0) { out[O_LB] = term; out[O_ZL] = zs / 16384.0f; }
  }
}

// ---------------------------------------------------------------------------
// Stable counting-sort scatter, split 8x by row-eighth: 512 blocks.
__global__ __launch_bounds__(256) void k_dispatch(const int* __restrict__ flat,
                                                  const int* __restrict__ offs2,
                                                  float* __restrict__ out) {
  __shared__ int wcs[4];
  const int e = blockIdx.x >> 3;
  const int q = blockIdx.x & 7;
  const int tid = threadIdx.x;
  const int lane = tid & 63;
  const int wv = tid >> 6;
  int base = offs2[e * 8 + q];
  const int seg0 = q * 16384;
  for (int c0 = 0; c0 < 16384; c0 += 2048) {
    const int j0 = seg0 + c0 + tid * 8;
    const int4* f4 = reinterpret_cast<const int4*>(flat + j0);
    int4 a = f4[0], b = f4[1];
    int v[8] = {a.x, a.y, a.z, a.w, b.x, b.y, b.z, b.w};
    int mcnt = 0;
#pragma unroll
    for (int k = 0; k < 8; ++k) mcnt += (v[k] == e) ? 1 : 0;
    int sc = mcnt;
#pragma unroll
    for (int o = 1; o < 64; o <<= 1) {
      int nn = __shfl_up(sc, o);
      if (lane >= o) sc += nn;
    }
    int excl = sc - mcnt;
    if (lane == 63) wcs[wv] = sc;
    __syncthreads();
    int woff = 0, tot = 0;
#pragma unroll
    for (int i = 0; i < 4; ++i) { int ci = wcs[i]; woff += (i < wv) ? ci : 0; tot += ci; }
    int pos = base + woff + excl;
#pragma unroll
    for (int k = 0; k < 8; ++k) {
      if (v[k] == e) { out[O_IDX + pos] = (float)(j0 + k); pos++; }
    }
    base += tot;
    __syncthreads();
  }
}

// ---------------------------------------------------------------------------
extern "C" void kernel_launch(void* const* d_in, const int* in_sizes, int n_in,
                              void* d_out, int out_size, void* d_ws, size_t ws_size,
                              hipStream_t stream) {
  (void)in_sizes; (void)n_in; (void)out_size; (void)ws_size;
  const float* x  = (const float*)d_in[0];
  const float* Wm = (const float*)d_in[1];
  float* out = (float*)d_out;
  char*  ws  = (char*)d_ws;

  int*    cq     = (int*)(ws + W_CQ);
  int*    gcount = (int*)(ws + W_GCOUNT);
  int*    offs2  = (int*)(ws + W_OFFS2);
  float*  lsqp   = (float*)(ws + W_LSQP);
  int*    list   = (int*)(ws + W_LIST);
  float*  psum   = (float*)(ws + W_PSUM);
  int*    flat   = (int*)(ws + W_FLAT);
  short8* wf     = (short8*)(ws + W_WF);
  float*  part   = (float*)(ws + W_PART);

  k_prep    <<<dim3(128), dim3(256), 0, stream>>>(Wm, wf, cq, gcount);
  k_gemm    <<<dim3(NTOK / 64, NSPLIT), dim3(256), 0, stream>>>(x, wf, part);
  k_rowtail <<<dim3(256), dim3(256), 0, stream>>>(part, out, cq, psum, lsqp, gcount, list, flat);
  k_repair  <<<dim3(256), dim3(256), 0, stream>>>(x, Wm, list, gcount, out, cq, flat);
  k_final   <<<dim3(1),   dim3(256), 0, stream>>>(cq, psum, lsqp, out, offs2);
  k_dispatch<<<dim3(512), dim3(256), 0, stream>>>(flat, offs2, out);
}

// Round 8
// 169.715 us; speedup vs baseline: 2.1647x; 1.2022x over previous
//
#include <hip/hip_runtime.h>
#include <hip/hip_bf16.h>
#include <math.h>

#define NTOK   16384
#define NEXP   64
#define HID    4096
#define KSEL   8
#define EPS    7.5e-5f
#define NSPLIT 4
#define KSZ    (HID / NSPLIT)

typedef __attribute__((ext_vector_type(8))) short short8;
typedef __attribute__((ext_vector_type(4))) float f32x4;

// d_out element offsets (f32 elements; int outputs stored as float values)
#define O_LOGITS 0u
#define O_PROBS  1048576u
#define O_TIDX   1179648u
#define O_GROUP  1310720u
#define O_IDX    1310784u
#define O_TPE    1441856u
#define O_LB     1441920u
#define O_ZL     1441921u

// ws byte offsets
#define W_CQ      0u          // 512 int: counts[q][e], q = row>>11
#define W_GCOUNT  2048u       // 1 int
#define W_OFFS2   4096u       // 512 int: offsets[e][q]
#define W_LSQP    8192u       // 256 f32 per-block z-loss partials
#define W_LIST    16384u      // 16384 int flagged rows
#define W_PSUM    81920u      // 256*128 f32 per-block half-tile probsum partials
#define W_FLAT    262144u     // 131072 int
#define W_WF      1048576u    // 1 MB: W packed as MFMA B-frags bf16 hi/lo
#define W_PART    2097152u    // NSPLIT x 4 MB f32 partials
#define PART_STRIDE 1048576ull

// round-to-nearest-even f32 -> bf16 bits
__device__ __forceinline__ unsigned short f2bf(float f) {
  unsigned u = __float_as_uint(f);
  return (unsigned short)((u + 0x7fffu + ((u >> 16) & 1u)) >> 16);
}

__device__ __forceinline__ void gload16(const void* g, void* l) {
  __builtin_amdgcn_global_load_lds((const __attribute__((address_space(1))) unsigned int*)g,
                                   (__attribute__((address_space(3))) unsigned int*)l, 16, 0, 0);
}

// ---------------------------------------------------------------------------
// prep: pack W into MFMA B-frags (bf16 hi/lo) + zero counters.
__global__ __launch_bounds__(256) void k_prep(const float* __restrict__ w,
                                              short8* __restrict__ wf,
                                              int* __restrict__ cq,
                                              int* __restrict__ gcount) {
  const int kk   = blockIdx.x;
  const int nb   = threadIdx.x >> 6;
  const int lane = threadIdx.x & 63;
  const int n    = nb * 16 + (lane & 15);
  const int kb   = kk * 32 + (lane >> 4) * 8;
  const float4* wp = (const float4*)(w + (size_t)n * HID + kb);
  float4 f0 = wp[0], f1 = wp[1];
  float fv[8] = {f0.x, f0.y, f0.z, f0.w, f1.x, f1.y, f1.z, f1.w};
  short8 hi, lo;
#pragma unroll
  for (int j = 0; j < 8; ++j) {
    unsigned short h = f2bf(fv[j]);
    hi[j] = (short)h;
    float r = fv[j] - __uint_as_float((unsigned)h << 16);
    lo[j] = (short)f2bf(r);
  }
  size_t base = ((size_t)(kk * 4 + nb) * 2) * 64 + lane;
  wf[base] = hi;
  wf[base + 64] = lo;
  if (blockIdx.x == 0) {
    cq[threadIdx.x] = 0;
    cq[threadIdx.x + 256] = 0;
    if (threadIdx.x == 0) gcount[0] = 0;
  }
}

// ---------------------------------------------------------------------------
// MFMA router GEMM, wf shared across waves via LDS (double-buffered,
// global_load_lds width-16, linear frag layout -> conflict-free ds_read_b128).
// 3-term bf16 Ozaki (ah*bh + al*bh + ah*bl). Grid (256,4) x 256 thr.
// Per-wave VMEM per chunk: 2 x-loads + 2 staged KB (vs 10 direct loads).
__global__ __launch_bounds__(256, 4) void k_gemm(const float* __restrict__ x,
                                                 const short8* __restrict__ wf,
                                                 float* __restrict__ part) {
  __shared__ short8 wl[2][512];   // 2 x 8 KB: frag f of chunk at wl[b][f*64+lane]
  const int tid  = threadIdx.x;
  const int wv   = tid >> 6;
  const int lane = tid & 63;
  const int t0   = blockIdx.x * 64;
  const int k0   = blockIdx.y * KSZ;
  const int row  = t0 + wv * 16 + (lane & 15);

  const float* xp = x + (size_t)row * HID + k0 + (lane >> 4) * 8;
  const short8* wbase = wf + (size_t)(k0 >> 5) * 512;   // this K-slice's frags

  // stage chunk c's 8 KB of frags into wl[b]; wave wv copies rounds of 1 KB.
  auto stage = [&](int c, int b) {
    const short8* src = wbase + (size_t)c * 512;
#pragma unroll
    for (int r = 0; r < 2; ++r) {
      const int o = r * 256 + wv * 64;        // short8 offset, wave-uniform
      gload16(src + o + lane, &wl[b][o]);     // lane offset added by HW
    }
  };

  f32x4 acc[4] = {{0,0,0,0},{0,0,0,0},{0,0,0,0},{0,0,0,0}};

  stage(0, 0);
  __syncthreads();
  const int nch = KSZ >> 5;   // 32
  for (int c = 0; c < nch; ++c) {
    const int b = c & 1;
    if (c + 1 < nch) stage(c + 1, b ^ 1);

    // x fragment: 8 consecutive f32, split into bf16 hi (trunc) + lo (RNE)
    const float4* xq = (const float4*)(xp + c * 32);
    float4 f0 = xq[0], f1 = xq[1];
    unsigned xb[8] = {__float_as_uint(f0.x), __float_as_uint(f0.y),
                      __float_as_uint(f0.z), __float_as_uint(f0.w),
                      __float_as_uint(f1.x), __float_as_uint(f1.y),
                      __float_as_uint(f1.z), __float_as_uint(f1.w)};
    union { unsigned u[4]; short8 s; } ua, ul;
#pragma unroll
    for (int p = 0; p < 4; ++p) {
      unsigned b0 = xb[2 * p], b1 = xb[2 * p + 1];
      ua.u[p] = __builtin_amdgcn_perm(b1, b0, 0x07060302u);
      float r0 = __uint_as_float(b0) - __uint_as_float(b0 & 0xffff0000u);
      float r1 = __uint_as_float(b1) - __uint_as_float(b1 & 0xffff0000u);
      unsigned t0b = __float_as_uint(r0), t1b = __float_as_uint(r1);
      t0b += 0x7fffu + ((t0b >> 16) & 1u);
      t1b += 0x7fffu + ((t1b >> 16) & 1u);
      ul.u[p] = __builtin_amdgcn_perm(t1b, t0b, 0x07060302u);
    }
    short8 ah = ua.s, al = ul.s;

#pragma unroll
    for (int nb = 0; nb < 4; ++nb) {
      short8 bh = wl[b][nb * 128 + lane];
      short8 bl = wl[b][nb * 128 + 64 + lane];
      acc[nb] = __builtin_amdgcn_mfma_f32_16x16x32_bf16(ah, bh, acc[nb], 0, 0, 0);
      acc[nb] = __builtin_amdgcn_mfma_f32_16x16x32_bf16(al, bh, acc[nb], 0, 0, 0);
      acc[nb] = __builtin_amdgcn_mfma_f32_16x16x32_bf16(ah, bl, acc[nb], 0, 0, 0);
    }
    __syncthreads();   // stage(c+1) landed; all waves done reading wl[b]
  }

  float* p = part + (size_t)blockIdx.y * PART_STRIDE;
  const int mrow = t0 + wv * 16 + (lane >> 4) * 4;
  const int col  = lane & 15;
#pragma unroll
  for (int nb = 0; nb < 4; ++nb)
#pragma unroll
    for (int r = 0; r < 4; ++r)
      p[(size_t)(mrow + r) * 64 + nb * 16 + col] = acc[nb][r];
}

// ---------------------------------------------------------------------------
// Fused reduce + rowwise. 256 blocks x 256 thr (4 waves).
__global__ __launch_bounds__(256) void k_rowtail(const float* __restrict__ part,
                                                 float* __restrict__ out,
                                                 int* __restrict__ cq,
                                                 float* __restrict__ psum,
                                                 float* __restrict__ lsqp,
                                                 int* __restrict__ gcount,
                                                 int* __restrict__ list,
                                                 int* __restrict__ flat) {
  __shared__ float tile[64][68];
  __shared__ float rmv[64], invv[64];
  __shared__ int   hist[64];
  const int bid  = blockIdx.x;
  const int tid  = threadIdx.x;
  const int wv   = tid >> 6;
  const int lane = tid & 63;
  const int t0   = bid * 64;
  if (tid < 64) hist[tid] = 0;

  {
    const size_t boff = (size_t)bid * 4096;
#pragma unroll
    for (int k = 0; k < 16; ++k) {
      int idx = k * 256 + tid;
      float v = part[boff + idx];
#pragma unroll
      for (int s = 1; s < NSPLIT; ++s) v += part[(size_t)s * PART_STRIDE + boff + idx];
      tile[idx >> 6][idx & 63] = v;
      out[O_LOGITS + boff + idx] = v;
    }
  }
  __syncthreads();

  // wave 1: per-row max, softmax denom, z-loss
  if (wv == 1) {
    const int r = lane;
    float rm = -3.0e38f;
#pragma unroll
    for (int c4 = 0; c4 < 16; ++c4) {
      float4 f = *(float4*)&tile[r][c4 * 4];
      rm = fmaxf(rm, fmaxf(fmaxf(f.x, f.y), fmaxf(f.z, f.w)));
    }
    float se = 0.0f;
#pragma unroll
    for (int c4 = 0; c4 < 16; ++c4) {
      float4 f = *(float4*)&tile[r][c4 * 4];
      se += expf(f.x - rm) + expf(f.y - rm) + expf(f.z - rm) + expf(f.w - rm);
    }
    rmv[r] = rm; invv[r] = 1.0f / se;
    float lse = rm + logf(se);
    float l2 = lse * lse;
#pragma unroll
    for (int o = 32; o > 0; o >>= 1) l2 += __shfl_down(l2, o);
    if (lane == 0) lsqp[bid] = l2;
  }
  __syncthreads();

  if (wv == 0) {
    // top-9 stable insertion on clipped keys + flag near-ties
    const unsigned t = t0 + lane;
    float val[9]; int idx[9];
#pragma unroll
    for (int j = 0; j < 9; ++j) { val[j] = -3.0e38f; idx[j] = 0; }
    bool flag = false;
#pragma unroll
    for (int c4 = 0; c4 < 16; ++c4) {
      float4 f = *(float4*)&tile[lane][c4 * 4];
      float fe[4] = {f.x, f.y, f.z, f.w};
#pragma unroll
      for (int jj = 0; jj < 4; ++jj) {
        float v = fe[jj];
        flag = flag || (fabsf(fabsf(v) - 2.0f) < EPS);
        float c = fminf(fmaxf(v, -2.0f), 2.0f);
        int id = c4 * 4 + jj;
#pragma unroll
        for (int j = 0; j < 9; ++j) {
          bool sw = c > val[j];
          float tv = sw ? val[j] : c; int ti = sw ? idx[j] : id;
          val[j] = sw ? c : val[j];   idx[j] = sw ? id : idx[j];
          c = tv; id = ti;
        }
      }
    }
#pragma unroll
    for (int j = 0; j < 8; ++j) {
      float gap = val[j] - val[j + 1];
      bool bothclip = (val[j] == val[j + 1]) && (fabsf(val[j]) == 2.0f);
      flag = flag || (gap < EPS && !bothclip);
    }
    if (!flag) {
      float m = val[0], pe[8], sum = 0.0f;
#pragma unroll
      for (int j = 0; j < 8; ++j) { pe[j] = expf(val[j] - m); sum += pe[j]; }
      float inv = 1.0f / sum;
      *(float4*)&out[O_PROBS + (size_t)t * 8]     = make_float4(pe[0]*inv, pe[1]*inv, pe[2]*inv, pe[3]*inv);
      *(float4*)&out[O_PROBS + (size_t)t * 8 + 4] = make_float4(pe[4]*inv, pe[5]*inv, pe[6]*inv, pe[7]*inv);
      *(float4*)&out[O_TIDX + (size_t)t * 8]      = make_float4((float)idx[0], (float)idx[1], (float)idx[2], (float)idx[3]);
      *(float4*)&out[O_TIDX + (size_t)t * 8 + 4]  = make_float4((float)idx[4], (float)idx[5], (float)idx[6], (float)idx[7]);
      *(int4*)&flat[(size_t)t * 8]     = make_int4(idx[0], idx[1], idx[2], idx[3]);
      *(int4*)&flat[(size_t)t * 8 + 4] = make_int4(idx[4], idx[5], idx[6], idx[7]);
#pragma unroll
      for (int j = 0; j < 8; ++j) atomicAdd(&hist[idx[j]], 1);
    } else {
      int sl = atomicAdd(gcount, 1);
      list[sl] = (int)t;
    }
  } else if (wv == 2 || wv == 3) {
    // softmax column half-sums (deterministic per-block partials)
    const int e = lane, half = wv - 2;
    float s = 0.0f;
#pragma unroll
    for (int r = 0; r < 32; ++r) {
      int rr = half * 32 + r;
      s += expf(tile[rr][e] - rmv[rr]) * invv[rr];
    }
    psum[(size_t)bid * 128 + half * 64 + e] = s;
  }
  __syncthreads();
  if (tid < 64) atomicAdd(&cq[(bid >> 5) * 64 + tid], hist[tid]);
}

// ---------------------------------------------------------------------------
// Exact f64 repair of flagged rows.
__global__ __launch_bounds__(256) void k_repair(const float* __restrict__ x,
                                                const float* __restrict__ w,
                                                const int* __restrict__ list,
                                                const int* __restrict__ gcount,
                                                float* __restrict__ out,
                                                int* __restrict__ cq,
                                                int* __restrict__ flat) {
  __shared__ double sh[4][64];
  __shared__ double tot[64];
  const int tid = threadIdx.x;
  const int wave = tid >> 6, lane = tid & 63;
  const int n = *gcount;
  for (int i = blockIdx.x; i < n; i += 256) {
    const int row = list[i];
    const float* xr = x + (size_t)row * HID;
    const float* wr = w + (size_t)lane * HID;
    double p0 = 0.0, p1 = 0.0, p2 = 0.0, p3 = 0.0;
    const int kb = wave * 1024;
    for (int k = kb; k < kb + 1024; k += 4) {
      float4 xv = *(const float4*)&xr[k];
      float4 wv = *(const float4*)&wr[k];
      p0 = fma((double)xv.x, (double)wv.x, p0);
      p1 = fma((double)xv.y, (double)wv.y, p1);
      p2 = fma((double)xv.z, (double)wv.z, p2);
      p3 = fma((double)xv.w, (double)wv.w, p3);
    }
    sh[wave][lane] = (p0 + p1) + (p2 + p3);
    __syncthreads();
    if (wave == 0) tot[lane] = (sh[0][lane] + sh[1][lane]) + (sh[2][lane] + sh[3][lane]);
    __syncthreads();
    if (tid == 0) {
      double val[8]; int idx[8];
#pragma unroll
      for (int j = 0; j < 8; ++j) { val[j] = -1.0e300; idx[j] = 0; }
      for (int e = 0; e < 64; ++e) {
        double c = fmin(fmax(tot[e], -2.0), 2.0);
        int id = e;
#pragma unroll
        for (int j = 0; j < 8; ++j) {
          bool sw = c > val[j];
          double tv = sw ? val[j] : c; int ti = sw ? idx[j] : id;
          val[j] = sw ? c : val[j];    idx[j] = sw ? id : idx[j];
          c = tv; id = ti;
        }
      }
      float m = (float)val[0], pe[8], sum = 0.0f;
#pragma unroll
      for (int j = 0; j < 8; ++j) { pe[j] = expf((float)val[j] - m); sum += pe[j]; }
      float inv = 1.0f / sum;
      const int q = row >> 11;
#pragma unroll
      for (int j = 0; j < 8; ++j) {
        out[O_PROBS + (size_t)row * 8 + j] = pe[j] * inv;
        out[O_TIDX  + (size_t)row * 8 + j] = (float)idx[j];
        flat[(size_t)row * 8 + j] = idx[j];
        atomicAdd(&cq[q * 64 + idx[j]], 1);
      }
    }
    __syncthreads();
  }
}

// ---------------------------------------------------------------------------
// cumsum/offsets + lb/z losses. 1 block x 256 threads.
__global__ __launch_bounds__(256) void k_final(const int* __restrict__ cq,
                                               const float* __restrict__ psum,
                                               const float* __restrict__ lsqp,
                                               float* __restrict__ out,
                                               int* __restrict__ offs2) {
  __shared__ int   ctot[64];
  __shared__ float gsum[4][64];
  const int tid = threadIdx.x;
  const int e = tid & 63, g = tid >> 6;

  if (tid < 64) {
    int tpe = 0;
#pragma unroll
    for (int q = 0; q < 8; ++q) tpe += cq[q * 64 + tid];
    ctot[tid] = tpe;
  }
  float ps = 0.0f;
  for (int b = g; b < 256; b += 4) ps += psum[(size_t)b * 128 + e] + psum[(size_t)b * 128 + 64 + e];
  gsum[g][e] = ps;
  __syncthreads();

  if (tid < 64) {
    int incl = 0;
    for (int i = 0; i <= tid; ++i) incl += ctot[i];
    int tpe = ctot[tid];
    out[O_TPE + tid]   = (float)tpe;
    out[O_GROUP + tid] = (float)incl;
    int o = incl - tpe;
#pragma unroll
    for (int q = 0; q < 8; ++q) { offs2[tid * 8 + q] = o; o += cq[q * 64 + tid]; }

    float pst = (gsum[0][tid] + gsum[1][tid]) + (gsum[2][tid] + gsum[3][tid]);
    float term = ((float)tpe / 131072.0f) * (pst / 16384.0f) * 64.0f;
#pragma unroll
    for (int o2 = 32; o2 > 0; o2 >>= 1) term += __shfl_down(term, o2);
    float zs = (lsqp[tid * 4] + lsqp[tid * 4 + 1]) + (lsqp[tid * 4 + 2] + lsqp[tid * 4 + 3]);
#pragma unroll
    for (int o2 = 32; o2 > 0; o2 >>= 1) zs += __shfl_down(zs, o2);
    if (tid == 0) { out[O_LB] = term; out[O_ZL] = zs / 16384.0f; }
  }
}

// ---------------------------------------------------------------------------
// Stable counting-sort scatter, split 8x by row-eighth: 512 blocks.
__global__ __launch_bounds__(256) void k_dispatch(const int* __restrict__ flat,
                                                  const int* __restrict__ offs2,
                                                  float* __restrict__ out) {
  __shared__ int wcs[4];
  const int e = blockIdx.x >> 3;
  const int q = blockIdx.x & 7;
  const int tid = threadIdx.x;
  const int lane = tid & 63;
  const int wv = tid >> 6;
  int base = offs2[e * 8 + q];
  const int seg0 = q * 16384;
  for (int c0 = 0; c0 < 16384; c0 += 2048) {
    const int j0 = seg0 + c0 + tid * 8;
    const int4* f4 = reinterpret_cast<const int4*>(flat + j0);
    int4 a = f4[0], b = f4[1];
    int v[8] = {a.x, a.y, a.z, a.w, b.x, b.y, b.z, b.w};
    int mcnt = 0;
#pragma unroll
    for (int k = 0; k < 8; ++k) mcnt += (v[k] == e) ? 1 : 0;
    int sc = mcnt;
#pragma unroll
    for (int o = 1; o < 64; o <<= 1) {
      int nn = __shfl_up(sc, o);
      if (lane >= o) sc += nn;
    }
    int excl = sc - mcnt;
    if (lane == 63) wcs[wv] = sc;
    __syncthreads();
    int woff = 0, tot = 0;
#pragma unroll
    for (int i = 0; i < 4; ++i) { int ci = wcs[i]; woff += (i < wv) ? ci : 0; tot += ci; }
    int pos = base + woff + excl;
#pragma unroll
    for (int k = 0; k < 8; ++k) {
      if (v[k] == e) { out[O_IDX + pos] = (float)(j0 + k); pos++; }
    }
    base += tot;
    __syncthreads();
  }
}

// ---------------------------------------------------------------------------
extern "C" void kernel_launch(void* const* d_in, const int* in_sizes, int n_in,
                              void* d_out, int out_size, void* d_ws, size_t ws_size,
                              hipStream_t stream) {
  (void)in_sizes; (void)n_in; (void)out_size; (void)ws_size;
  const float* x  = (const float*)d_in[0];
  const float* Wm = (const float*)d_in[1];
  float* out = (float*)d_out;
  char*  ws  = (char*)d_ws;

  int*    cq     = (int*)(ws + W_CQ);
  int*    gcount = (int*)(ws + W_GCOUNT);
  int*    offs2  = (int*)(ws + W_OFFS2);
  float*  lsqp   = (float*)(ws + W_LSQP);
  int*    list   = (int*)(ws + W_LIST);
  float*  psum   = (float*)(ws + W_PSUM);
  int*    flat   = (int*)(ws + W_FLAT);
  short8* wf     = (short8*)(ws + W_WF);
  float*  part   = (float*)(ws + W_PART);

  k_prep    <<<dim3(128), dim3(256), 0, stream>>>(Wm, wf, cq, gcount);
  k_gemm    <<<dim3(NTOK / 64, NSPLIT), dim3(256), 0, stream>>>(x, wf, part);
  k_rowtail <<<dim3(256), dim3(256), 0, stream>>>(part, out, cq, psum, lsqp, gcount, list, flat);
  k_repair  <<<dim3(256), dim3(256), 0, stream>>>(x, Wm, list, gcount, out, cq, flat);
  k_final   <<<dim3(1),   dim3(256), 0, stream>>>(cq, psum, lsqp, out, offs2);
  k_dispatch<<<dim3(512), dim3(256), 0, stream>>>(flat, offs2, out);
}